// Round 11
// baseline (1396.346 us; speedup 1.0000x reference)
//
#include <hip/hip_runtime.h>

#define NBATCH 16
#define NPTS   4096
#define NSAMP  1024
#define NKNN   32
#define NROWS  (NBATCH*NSAMP*NKNN)   // 524288
#define BN_EPS 1e-5f
#define H1PAD  66
#define KNN_CAP 512

typedef __attribute__((ext_vector_type(4))) float f32x4;
typedef __attribute__((ext_vector_type(8))) short bf16x8;
union frag_u { unsigned u[4]; bf16x8 h; uint4 u4; };

__device__ __forceinline__ unsigned pack_bf16pair(float a, float b) {
    unsigned ua = __float_as_uint(a); ua += 0x7FFFu + ((ua >> 16) & 1u);
    unsigned ub = __float_as_uint(b); ub += 0x7FFFu + ((ub >> 16) & 1u);
    return (ua >> 16) | (ub & 0xFFFF0000u);
}

// ============================ FPS v5 ============================
// (validated rounds 1-10; at structural latency floor ~650us — untouched)
__global__ __launch_bounds__(256) void fps_kernel(const float* __restrict__ xyz,
                                                  float* __restrict__ newxyz)
{
    const int b = blockIdx.x;
    const int tid = threadIdx.x;
    const int wv = tid >> 6;          // 0..3
    const float* xb = xyz + (size_t)b * NPTS * 3;
    __shared__ float xs[NPTS];
    __shared__ float ys[NPTS];
    __shared__ float zs[NPTS];
    __shared__ __align__(16) float4 red[2][4];   // (maxval, x, y, z)
    __shared__ __align__(16) float nxs[NSAMP*3]; // 12 KB output staging
    float px[16], py[16], pz[16], dmin[16];
    {
        float arr[48];
        const float4* s4 = (const float4*)(xb + (size_t)tid * 48);
        #pragma unroll
        for (int i = 0; i < 12; ++i) *(float4*)&arr[i*4] = s4[i];
        #pragma unroll
        for (int j = 0; j < 16; ++j) {
            px[j] = arr[3*j]; py[j] = arr[3*j+1]; pz[j] = arr[3*j+2];
            const int p = tid * 16 + j;
            xs[p] = px[j]; ys[p] = py[j]; zs[p] = pz[j];
            dmin[j] = 1e10f;
        }
    }
    if (tid == 0) { nxs[0] = xb[0]; nxs[1] = xb[1]; nxs[2] = xb[2]; }
    __syncthreads();
    float lx = xs[0], ly = ys[0], lz = zs[0];
    for (int t = 1; t < NSAMP; ++t) {
        float bv = -1.0f;
        #pragma unroll
        for (int j = 0; j < 16; ++j) {
            const float dx = __fsub_rn(px[j], lx);
            const float dy = __fsub_rn(py[j], ly);
            const float dz = __fsub_rn(pz[j], lz);
            const float d = __fadd_rn(__fadd_rn(__fmul_rn(dx,dx), __fmul_rn(dy,dy)), __fmul_rn(dz,dz));
            const float nd = fminf(dmin[j], d);
            dmin[j] = nd;
            bv = fmaxf(bv, nd);
        }
        int lj = 0;
        #pragma unroll
        for (int j = 15; j >= 0; --j) if (dmin[j] == bv) lj = j;
        const int bi_lane = tid * 16 + lj;
        float mv = bv;
        {
            int s_;
            s_ = __builtin_amdgcn_mov_dpp(__float_as_int(mv), 0x111, 0xf, 0xf, true);
            mv = fmaxf(mv, __int_as_float(s_));
            s_ = __builtin_amdgcn_mov_dpp(__float_as_int(mv), 0x112, 0xf, 0xf, true);
            mv = fmaxf(mv, __int_as_float(s_));
            s_ = __builtin_amdgcn_mov_dpp(__float_as_int(mv), 0x114, 0xf, 0xf, true);
            mv = fmaxf(mv, __int_as_float(s_));
            s_ = __builtin_amdgcn_mov_dpp(__float_as_int(mv), 0x118, 0xf, 0xf, true);
            mv = fmaxf(mv, __int_as_float(s_));
            s_ = __builtin_amdgcn_mov_dpp(__float_as_int(mv), 0x142, 0xf, 0xf, true);
            mv = fmaxf(mv, __int_as_float(s_));
            s_ = __builtin_amdgcn_mov_dpp(__float_as_int(mv), 0x143, 0xf, 0xf, true);
            mv = fmaxf(mv, __int_as_float(s_));
        }
        mv = __int_as_float(__builtin_amdgcn_readlane(__float_as_int(mv), 63));
        const unsigned long long mask = __ballot(bv == mv);
        const int winner = __ffsll(mask) - 1;
        const int bi_w = __builtin_amdgcn_readlane(bi_lane, winner);
        const float wx = xs[bi_w], wy = ys[bi_w], wz = zs[bi_w];
        const int par = t & 1;
        if ((tid & 63) == 0) red[par][wv] = make_float4(mv, wx, wy, wz);
        __syncthreads();
        float4 w0 = red[par][0];
        const float4 w1 = red[par][1];
        const float4 w2 = red[par][2];
        const float4 w3 = red[par][3];
        if (w1.x > w0.x) w0 = w1;
        if (w2.x > w0.x) w0 = w2;
        if (w3.x > w0.x) w0 = w3;
        lx = w0.y; ly = w0.z; lz = w0.w;
        if (tid == 0) { nxs[t*3] = lx; nxs[t*3+1] = ly; nxs[t*3+2] = lz; }
    }
    __syncthreads();
    {
        float4* d4 = (float4*)(newxyz + (size_t)b * NSAMP * 3);
        const float4* s4 = (const float4*)nxs;
        #pragma unroll
        for (int i = tid; i < NSAMP*3/4; i += 256) d4[i] = s4[i];
    }
}

// ============================ kNN v2 ============================
// (validated round 10 — parallel bin-select + candidate compaction)
__device__ __forceinline__ void bin_select(int* hist, int* ctrl, int* wsum,
                                           int tid, int shift)
{
    const int lane = tid & 63, wv = tid >> 6;
    const int cnt = hist[tid];
    const int r = ctrl[1];            // read old r BEFORE the barrier
    int incl = cnt;
    #pragma unroll
    for (int d = 1; d < 64; d <<= 1) {
        const int v = __shfl_up(incl, d);
        if (lane >= d) incl += v;
    }
    if (lane == 63) wsum[wv] = incl;
    __syncthreads();
    int base = 0;
    if (wv > 0) base += wsum[0];
    if (wv > 1) base += wsum[1];
    if (wv > 2) base += wsum[2];
    incl += base;
    const int excl = incl - cnt;
    if (excl < r && r <= incl) {      // exactly one thread
        ctrl[0] |= tid << shift;
        ctrl[1] = r - excl;
        ctrl[2] = cnt;
    }
}

__global__ __launch_bounds__(256) void knn_kernel(const float* __restrict__ xyz,
                                                  const float* __restrict__ newxyz,
                                                  int* __restrict__ idx_out)
{
    const int bs = blockIdx.x;
    const int b = bs >> 10;
    const int tid = threadIdx.x;
    __shared__ unsigned keys[NPTS];   // 16 KB
    __shared__ int hist[256];
    __shared__ float qsh[3];
    __shared__ int ctrl[8];           // 0:pf 1:r 2:selCnt 3:eqn 4:ltn 5:outn 6:tien
    __shared__ int wsum[4];
    __shared__ int cl[KNN_CAP];
    __shared__ int lt[32];
    __shared__ int ties[128];
    if (tid < 3) qsh[tid] = newxyz[bs*3 + tid];
    if (tid == 0) { ctrl[0] = 0; ctrl[1] = NKNN; }
    hist[tid] = 0;
    __syncthreads();
    const float q0 = qsh[0], q1 = qsh[1], q2 = qsh[2];
    const float qq = __fadd_rn(__fadd_rn(__fmul_rn(q0,q0), __fmul_rn(q1,q1)), __fmul_rn(q2,q2));
    const float* xb = xyz + (size_t)b * NPTS * 3;
    for (int n = tid; n < NPTS; n += 256) {
        const float x0 = xb[n*3+0], x1 = xb[n*3+1], x2 = xb[n*3+2];
        const float xx = __fadd_rn(__fadd_rn(__fmul_rn(x0,x0), __fmul_rn(x1,x1)), __fmul_rn(x2,x2));
        float dt = __fmul_rn(q0, x0);
        dt = __fmaf_rn(q1, x1, dt);
        dt = __fmaf_rn(q2, x2, dt);
        const float dd = __fadd_rn(__fsub_rn(qq, __fmul_rn(2.0f, dt)), xx);
        unsigned ub = __float_as_uint(dd);
        ub = (ub & 0x80000000u) ? ~ub : (ub | 0x80000000u);
        keys[n] = ub;
        atomicAdd(&hist[ub >> 24], 1);
    }
    __syncthreads();
    bin_select(hist, ctrl, wsum, tid, 24);
    __syncthreads();
    const unsigned pf3 = (unsigned)ctrl[0];
    const int bin3 = (int)(pf3 >> 24);
    const int m = ctrl[2];
    const bool compact = (m <= KNN_CAP);
    if (tid == 0) { ctrl[3] = 0; ctrl[4] = 0; ctrl[5] = 0; ctrl[6] = 0; }
    __syncthreads();
    if (compact) {
        for (int n = tid; n < NPTS; n += 256) {
            const int tb = (int)(keys[n] >> 24);
            if (tb == bin3)      { const int pos = atomicAdd(&ctrl[3], 1); cl[pos] = n; }
            else if (tb < bin3)  { const int pos = atomicAdd(&ctrl[4], 1); lt[pos] = n; }
        }
    }
    __syncthreads();
    for (int p = 2; p >= 0; --p) {
        hist[tid] = 0;
        __syncthreads();
        const unsigned pre = (unsigned)ctrl[0];
        const int shift = p * 8;
        const unsigned himask = 0xFFFFFFFFu << ((p + 1) * 8);
        if (compact) {
            const int eqn = ctrl[3];
            for (int i = tid; i < eqn; i += 256) {
                const unsigned k = keys[cl[i]];
                if ((k & himask) == pre) atomicAdd(&hist[(k >> shift) & 255], 1);
            }
        } else {
            for (int n = tid; n < NPTS; n += 256) {
                const unsigned k = keys[n];
                if ((k & himask) == pre) atomicAdd(&hist[(k >> shift) & 255], 1);
            }
        }
        __syncthreads();
        bin_select(hist, ctrl, wsum, tid, shift);
        __syncthreads();
    }
    const unsigned T = (unsigned)ctrl[0];
    int* out = idx_out + (size_t)bs * NKNN;
    if (compact) {
        const int ltn = ctrl[4];
        if (tid == 0) ctrl[5] = ltn;
        __syncthreads();
        if (tid < ltn) out[tid] = lt[tid];
        const int eqn = ctrl[3];
        for (int i = tid; i < eqn; i += 256) {
            const int n = cl[i];
            const unsigned k = keys[n];
            if (k < T) {
                const int pos = atomicAdd(&ctrl[5], 1);
                if (pos < NKNN) out[pos] = n;
            } else if (k == T) {
                const int pos = atomicAdd(&ctrl[6], 1);
                if (pos < 128) ties[pos] = n;
            }
        }
    } else {
        for (int n = tid; n < NPTS; n += 256) {
            const unsigned k = keys[n];
            if (k < T) {
                const int pos = atomicAdd(&ctrl[5], 1);
                if (pos < NKNN) out[pos] = n;
            } else if (k == T) {
                const int pos = atomicAdd(&ctrl[6], 1);
                if (pos < 128) ties[pos] = n;
            }
        }
    }
    __syncthreads();
    if (tid == 0) {
        const int nless = ctrl[5] < NKNN ? ctrl[5] : NKNN;
        const int need = NKNN - nless;
        const int ntie = ctrl[6] < 128 ? ctrl[6] : 128;
        int last = -1;
        for (int j = 0; j < need; ++j) {
            int best = 0x7fffffff;
            for (int i = 0; i < ntie; ++i) {
                const int v = ties[i];
                if (v > last && v < best) best = v;
            }
            out[nless + j] = (best == 0x7fffffff) ? 0 : best;
            last = best;
        }
    }
}

// ============================ zero / moments ============================
__global__ void zero_all_kernel(double* st, float* g1, float* g2)
{
    const int i = blockIdx.x * 256 + threadIdx.x;
    if (i < 512) st[i] = 0.0;
    if (i < 4096) { g1[i] = 0.f; g2[i] = 0.f; }
}

// f32 per-thread partials (2 rows/thread at grid 1024), f64 reduce.
__global__ __launch_bounds__(256) void gxmoments_kernel(
    const float* __restrict__ xyz, const float* __restrict__ newxyz,
    const int* __restrict__ idxws, double* __restrict__ stats)
{
    const int tid = threadIdx.x;
    float m[9];
    #pragma unroll
    for (int i = 0; i < 9; ++i) m[i] = 0.f;
    for (int row = blockIdx.x * 256 + tid; row < NROWS; row += gridDim.x * 256) {
        const int bs = row >> 5;
        const int bb = row >> 15;
        const int id = idxws[row];
        const float* xp = xyz + ((size_t)bb * NPTS + id) * 3;
        const float* qp = newxyz + bs * 3;
        const float dx = xp[0] - qp[0];
        const float dy = xp[1] - qp[1];
        const float dz = xp[2] - qp[2];
        m[0] += dx; m[1] += dy; m[2] += dz;
        m[3] += dx*dx; m[4] += dx*dy; m[5] += dx*dz;
        m[6] += dy*dy; m[7] += dy*dz; m[8] += dz*dz;
    }
    double d[9];
    #pragma unroll
    for (int i = 0; i < 9; ++i) {
        d[i] = (double)m[i];
        #pragma unroll
        for (int s = 1; s < 64; s <<= 1) d[i] += __shfl_xor(d[i], s);
    }
    __shared__ double part[4][9];
    if ((tid & 63) == 0) {
        #pragma unroll
        for (int i = 0; i < 9; ++i) part[tid >> 6][i] = d[i];
    }
    __syncthreads();
    if (tid < 9) atomicAdd(&stats[tid], part[0][tid] + part[1][tid] + part[2][tid] + part[3][tid]);
}

__global__ void bn0_moments_finalize_kernel(const double* __restrict__ st,
    const float* __restrict__ w0, const float* __restrict__ b0,
    const float* __restrict__ g0, const float* __restrict__ be0,
    float* __restrict__ outp)
{
    const int c = threadIdx.x;  // 64
    const double N = (double)NROWS;
    const double w0c = w0[c], w1c = w0[64 + c], w2c = w0[128 + c];
    const double b = b0[c];
    const double dotS = st[0]*w0c + st[1]*w1c + st[2]*w2c;
    const double qf = w0c*w0c*st[3] + w1c*w1c*st[6] + w2c*w2c*st[8]
                    + 2.0*(w0c*w1c*st[4] + w0c*w2c*st[5] + w1c*w2c*st[7]);
    const double mean = dotS / N + b;
    const double ex2 = (qf + 2.0*b*dotS) / N + b*b;
    const double var = ex2 - mean*mean;
    const float scale = g0[c] * rsqrtf((float)var + BN_EPS);
    outp[c] = scale;
    outp[64 + c] = be0[c] - (float)mean * scale;
}

// ============================ weight pre-pack (all three in one launch) ====
__global__ void wfpack_all_kernel(const float* __restrict__ wf,
                                  const float* __restrict__ w1,
                                  const float* __restrict__ w2,
                                  unsigned* __restrict__ wfb,
                                  unsigned* __restrict__ w1b,
                                  unsigned* __restrict__ w2b)
{
    int blk = blockIdx.x;            // 0-511: wf, 512-519: w1, 520-527: w2
    const float* src; unsigned* dst;
    if (blk < 512)      { src = wf; dst = wfb; }
    else if (blk < 520) { src = w1; dst = w1b; blk -= 512; }
    else                { src = w2; dst = w2b; blk -= 520; }
    const int kt = blk >> 2, ot = blk & 3;
    const int l = threadIdx.x;            // 64
    const int o = ot*16 + (l & 15);
    const int kb = kt*32 + (l >> 4)*8;
    unsigned out[4];
    #pragma unroll
    for (int r = 0; r < 4; ++r) {
        const float a = src[(size_t)(kb + 2*r) * 64 + o];
        const float b = src[(size_t)(kb + 2*r + 1) * 64 + o];
        out[r] = pack_bf16pair(a, b);
    }
    *(uint4*)&dst[((size_t)blk * 64 + l) * 4] = *(const uint4*)out;
}

// ============================ Gram stats ============================
__global__ __launch_bounds__(256) void gram1_kernel(
    const float* __restrict__ xyz, const float* __restrict__ newxyz,
    const int* __restrict__ idxws,
    const float* __restrict__ w0, const float* __restrict__ b0,
    const float* __restrict__ bnp, float* __restrict__ G1,
    double* __restrict__ Sh1)
{
    __shared__ float gxs[32][3];
    __shared__ float h1s[32][H1PAD];
    __shared__ float rsum[256];
    const int tid = threadIdx.x;
    const int c = tid & 63;
    const int rq = tid >> 6;
    const int lg = c >> 4, lm = c & 15;
    const float w0c0 = w0[c], w0c1 = w0[64+c], w0c2 = w0[128+c];
    const float b0c = b0[c], sc0 = bnp[c], sh0 = bnp[64+c];
    f32x4 Ga[4] = {{0,0,0,0},{0,0,0,0},{0,0,0,0},{0,0,0,0}};
    float sumh = 0.f;
    for (int chunk = blockIdx.x; chunk < NROWS/32; chunk += gridDim.x) {
        if (tid < 96) {
            const int slot = tid / 3, cc = tid % 3;
            const int row = chunk*32 + slot;
            const int bs = row >> 5, bb = row >> 15;
            gxs[slot][cc] = xyz[((size_t)bb * NPTS + idxws[row]) * 3 + cc] - newxyz[bs*3 + cc];
        }
        __syncthreads();
        #pragma unroll
        for (int i = 0; i < 8; ++i) {
            const int r = rq*8 + i;
            const float t0 = gxs[r][0]*w0c0 + gxs[r][1]*w0c1 + gxs[r][2]*w0c2 + b0c;
            const float h = fmaxf(sc0*t0 + sh0, 0.f);
            h1s[r][c] = h;
            sumh += h;
        }
        __syncthreads();
        frag_u fr[4];
        #pragma unroll
        for (int ct = 0; ct < 4; ++ct)
            #pragma unroll
            for (int r = 0; r < 4; ++r)
                fr[ct].u[r] = pack_bf16pair(h1s[lg*8 + 2*r][ct*16 + lm],
                                            h1s[lg*8 + 2*r + 1][ct*16 + lm]);
        #pragma unroll
        for (int ct = 0; ct < 4; ++ct)
            Ga[ct] = __builtin_amdgcn_mfma_f32_16x16x32_bf16(fr[rq].h, fr[ct].h, Ga[ct], 0, 0, 0);
        __syncthreads();
    }
    #pragma unroll
    for (int ct = 0; ct < 4; ++ct)
        #pragma unroll
        for (int r = 0; r < 4; ++r)
            atomicAdd(&G1[(rq*16 + lg*4 + r)*64 + ct*16 + lm], Ga[ct][r]);
    rsum[tid] = sumh;
    __syncthreads();
    if (tid < 64) atomicAdd(&Sh1[c], (double)(rsum[c] + rsum[64+c] + rsum[128+c] + rsum[192+c]));
}

__global__ __launch_bounds__(256) void gram2_kernel(
    const float* __restrict__ xyz, const float* __restrict__ newxyz,
    const int* __restrict__ idxws,
    const float* __restrict__ w0, const float* __restrict__ b0,
    const float* __restrict__ b1, const unsigned* __restrict__ w1b,
    const float* __restrict__ bnp, float* __restrict__ G2,
    double* __restrict__ Sh2)
{
    __shared__ float gxs[32][3];
    __shared__ float h1s[32][H1PAD];
    __shared__ float h2s[32][H1PAD];
    __shared__ float rsum[256];
    const int tid = threadIdx.x;
    const int c = tid & 63;
    const int rq = tid >> 6;
    const int lg = c >> 4, lm = c & 15;
    const int c2 = rq*16 + lm;
    const float w0c0 = w0[c], w0c1 = w0[64+c], w0c2 = w0[128+c];
    const float b0c = b0[c], sc0 = bnp[c], sh0 = bnp[64+c];
    const float b1c2 = b1[c2], sc1 = bnp[128+c2], sh1 = bnp[192+c2];
    frag_u Bw1[2];
    Bw1[0].u4 = *(const uint4*)&w1b[((0*4 + rq)*64 + c)*4];
    Bw1[1].u4 = *(const uint4*)&w1b[((1*4 + rq)*64 + c)*4];
    f32x4 Ga[4] = {{0,0,0,0},{0,0,0,0},{0,0,0,0},{0,0,0,0}};
    float sumh = 0.f;
    for (int chunk = blockIdx.x; chunk < NROWS/32; chunk += gridDim.x) {
        if (tid < 96) {
            const int slot = tid / 3, cc = tid % 3;
            const int row = chunk*32 + slot;
            const int bs = row >> 5, bb = row >> 15;
            gxs[slot][cc] = xyz[((size_t)bb * NPTS + idxws[row]) * 3 + cc] - newxyz[bs*3 + cc];
        }
        __syncthreads();
        #pragma unroll
        for (int i = 0; i < 8; ++i) {
            const int r = rq*8 + i;
            const float t0 = gxs[r][0]*w0c0 + gxs[r][1]*w0c1 + gxs[r][2]*w0c2 + b0c;
            h1s[r][c] = fmaxf(sc0*t0 + sh0, 0.f);
        }
        __syncthreads();
        #pragma unroll
        for (int mt = 0; mt < 2; ++mt) {
            f32x4 acc = {0,0,0,0};
            #pragma unroll
            for (int kt = 0; kt < 2; ++kt) {
                frag_u a;
                #pragma unroll
                for (int r = 0; r < 4; ++r) {
                    const float2 f = *(const float2*)&h1s[mt*16 + lm][kt*32 + lg*8 + 2*r];
                    a.u[r] = pack_bf16pair(f.x, f.y);
                }
                acc = __builtin_amdgcn_mfma_f32_16x16x32_bf16(a.h, Bw1[kt].h, acc, 0, 0, 0);
            }
            #pragma unroll
            for (int r = 0; r < 4; ++r)
                h2s[mt*16 + lg*4 + r][c2] = fmaxf(sc1*(acc[r] + b1c2) + sh1, 0.f);
        }
        __syncthreads();
        #pragma unroll
        for (int i = 0; i < 8; ++i) sumh += h2s[rq*8 + i][c];
        frag_u fr[4];
        #pragma unroll
        for (int ct = 0; ct < 4; ++ct)
            #pragma unroll
            for (int r = 0; r < 4; ++r)
                fr[ct].u[r] = pack_bf16pair(h2s[lg*8 + 2*r][ct*16 + lm],
                                            h2s[lg*8 + 2*r + 1][ct*16 + lm]);
        #pragma unroll
        for (int ct = 0; ct < 4; ++ct)
            Ga[ct] = __builtin_amdgcn_mfma_f32_16x16x32_bf16(fr[rq].h, fr[ct].h, Ga[ct], 0, 0, 0);
        __syncthreads();
    }
    #pragma unroll
    for (int ct = 0; ct < 4; ++ct)
        #pragma unroll
        for (int r = 0; r < 4; ++r)
            atomicAdd(&G2[(rq*16 + lg*4 + r)*64 + ct*16 + lm], Ga[ct][r]);
    rsum[tid] = sumh;
    __syncthreads();
    if (tid < 64) atomicAdd(&Sh2[c], (double)(rsum[c] + rsum[64+c] + rsum[128+c] + rsum[192+c]));
}

__global__ __launch_bounds__(256) void bn_gram_finalize_kernel(
    const double* __restrict__ Sh, const float* __restrict__ G,
    const float* __restrict__ w, const float* __restrict__ bias,
    const float* __restrict__ g, const float* __restrict__ be,
    float* __restrict__ outp)
{
    __shared__ float wls[64][65];
    __shared__ double shl[64];
    __shared__ double rd[256], rqd[256];
    const int tid = threadIdx.x;
    const int c = tid & 63;
    const int rqi = tid >> 6;
    for (int i = tid; i < 4096; i += 256) wls[i >> 6][i & 63] = w[i];
    if (tid < 64) shl[tid] = Sh[tid];
    __syncthreads();
    double dot = 0.0, quad = 0.0;
    for (int j = rqi*16; j < rqi*16 + 16; ++j) {
        const double wjc = (double)wls[j][c];
        dot += wjc * shl[j];
        double inner = 0.0;
        for (int k = 0; k < 64; ++k) inner += (double)G[j*64 + k] * (double)wls[k][c];
        quad += wjc * inner;
    }
    rd[tid] = dot; rqd[tid] = quad;
    __syncthreads();
    if (tid < 64) {
        const double d = rd[c] + rd[64+c] + rd[128+c] + rd[192+c];
        const double q = rqd[c] + rqd[64+c] + rqd[128+c] + rqd[192+c];
        const double N = (double)NROWS;
        const double bc = (double)bias[c];
        const double mean = d / N + bc;
        const double ex2 = (q + 2.0*bc*d) / N + bc*bc;
        const double var = ex2 - mean*mean;
        const float scale = g[c] * rsqrtf((float)var + BN_EPS);
        outp[c] = scale;
        outp[64 + c] = be[c] - (float)mean * scale;
    }
}

__global__ void bn_finalize_kernel(const double* __restrict__ st,
                                   const float* __restrict__ g,
                                   const float* __restrict__ be,
                                   float* __restrict__ outp, float n)
{
    const int c = threadIdx.x;  // 64
    const double m = st[c] / (double)n;
    const double var = st[64 + c] / (double)n - m * m;
    const float scale = g[c] * rsqrtf((float)var + BN_EPS);
    outp[c] = scale;
    outp[64 + c] = be[c] - (float)m * scale;
}

// ============================ final fused conv ============================
// r11: all gxs hoisted upfront (one latency exposure, -4 barriers); y-loop
// uses dual accumulators (even/odd kt) to double the MFMA chain ILP.
__global__ __launch_bounds__(256) void final_conv_kernel(
    const float* __restrict__ xyz, const float* __restrict__ newxyz,
    const int* __restrict__ idxws, const float* __restrict__ feat,
    const float* __restrict__ w0, const float* __restrict__ b0,
    const float* __restrict__ b1, const float* __restrict__ b2,
    const float* __restrict__ bnp, const unsigned* __restrict__ wfb,
    const unsigned* __restrict__ w1b, const unsigned* __restrict__ w2b,
    const float* __restrict__ bf, float* __restrict__ y)
{
    __shared__ unsigned wtp[8][16][64];
    __shared__ __align__(16) float scratch[2*64*H1PAD];
    __shared__ float gxs[256][3];
    __shared__ int   idxs[8][32];
    __shared__ float qs[8][3];
    float* h1s = scratch;
    float* h2s = scratch + 64*H1PAD;
    unsigned* yaf = (unsigned*)scratch;
    const int tid = threadIdx.x;
    const int c = tid & 63;
    const int rq = tid >> 6;
    const int lg = c >> 4, lm = c & 15;
    const int c2 = rq*16 + lm;
    const int bs0 = blockIdx.x * 8;
    const int b = bs0 >> 10;
    idxs[tid >> 5][tid & 31] = idxws[(size_t)bs0 * NKNN + tid];
    if (tid < 24)  qs[tid / 3][tid % 3] = newxyz[(bs0 + tid/3)*3 + (tid % 3)];
    const float w0c0 = w0[c], w0c1 = w0[64+c], w0c2 = w0[128+c];
    const float b0c = b0[c], sc0 = bnp[c], sh0 = bnp[64+c];
    const float b1c2 = b1[c2], sc1 = bnp[128+c2], sh1 = bnp[192+c2];
    const float b2c2 = b2[c2], sc2 = bnp[256+c2], sh2 = bnp[320+c2];
    frag_u Bw1[2], Bw2[2];
    #pragma unroll
    for (int kt = 0; kt < 2; ++kt) {
        Bw1[kt].u4 = *(const uint4*)&w1b[((kt*4 + rq)*64 + c)*4];
        Bw2[kt].u4 = *(const uint4*)&w2b[((kt*4 + rq)*64 + c)*4];
    }
    __syncthreads();
    // all 256 gather rows upfront (one global-latency exposure)
    for (int i = tid; i < 768; i += 256) {
        const int row = i / 3, cc = i - row * 3;
        const int e = row >> 5, k = row & 31;
        gxs[row][cc] = xyz[((size_t)b * NPTS + idxs[e][k]) * 3 + cc] - qs[e][cc];
    }
    __syncthreads();
    for (int chunk = 0; chunk < 4; ++chunk) {
        #pragma unroll
        for (int i = 0; i < 16; ++i) {
            const int r = rq*16 + i;
            const int gr = chunk*64 + r;
            const float t0 = gxs[gr][0]*w0c0 + gxs[gr][1]*w0c1 + gxs[gr][2]*w0c2 + b0c;
            h1s[r*H1PAD + c] = fmaxf(sc0*t0 + sh0, 0.f);
        }
        __syncthreads();
        #pragma unroll
        for (int mt = 0; mt < 4; ++mt) {
            f32x4 acc = {0,0,0,0};
            #pragma unroll
            for (int kt = 0; kt < 2; ++kt) {
                frag_u a;
                #pragma unroll
                for (int r = 0; r < 4; ++r) {
                    const float2 f = *(const float2*)&h1s[(mt*16 + lm)*H1PAD + kt*32 + lg*8 + 2*r];
                    a.u[r] = pack_bf16pair(f.x, f.y);
                }
                acc = __builtin_amdgcn_mfma_f32_16x16x32_bf16(a.h, Bw1[kt].h, acc, 0, 0, 0);
            }
            #pragma unroll
            for (int r = 0; r < 4; ++r)
                h2s[(mt*16 + lg*4 + r)*H1PAD + c2] = fmaxf(sc1*(acc[r] + b1c2) + sh1, 0.f);
        }
        __syncthreads();
        #pragma unroll
        for (int mt = 0; mt < 4; ++mt) {
            f32x4 acc = {0,0,0,0};
            #pragma unroll
            for (int kt = 0; kt < 2; ++kt) {
                frag_u a;
                #pragma unroll
                for (int r = 0; r < 4; ++r) {
                    const float2 f = *(const float2*)&h2s[(mt*16 + lm)*H1PAD + kt*32 + lg*8 + 2*r];
                    a.u[r] = pack_bf16pair(f.x, f.y);
                }
                acc = __builtin_amdgcn_mfma_f32_16x16x32_bf16(a.h, Bw2[kt].h, acc, 0, 0, 0);
            }
            float wt[4];
            #pragma unroll
            for (int r = 0; r < 4; ++r)
                wt[r] = fmaxf(sc2*(acc[r] + b2c2) + sh2, 0.f);
            const int grow0 = chunk*64 + mt*16 + lg*4;
            const int e = grow0 >> 5, kl = grow0 & 31;
            wtp[e][kl >> 1][c2]       = pack_bf16pair(wt[0], wt[1]);
            wtp[e][(kl >> 1) + 1][c2] = pack_bf16pair(wt[2], wt[3]);
        }
        __syncthreads();
    }
    const int lane = c;
    const int wid = rq;
    frag_u afr[2][4];
    #pragma unroll
    for (int es = 0; es < 2; ++es)
        #pragma unroll
        for (int w4 = 0; w4 < 4; ++w4)
            #pragma unroll
            for (int r = 0; r < 4; ++r)
                afr[es][w4].u[r] = wtp[wid*2 + es][lg*4 + r][w4*16 + lm];
    f32x4 yaccA = {0.f, 0.f, 0.f, 0.f};
    f32x4 yaccB = {0.f, 0.f, 0.f, 0.f};
    for (int dhalf = 0; dhalf < 2; ++dhalf) {
        #pragma unroll
        for (int es = 0; es < 2; ++es) {
            const int e = wid*2 + es;
            #pragma unroll
            for (int dt = 0; dt < 2; ++dt) {
                const int d = dhalf*32 + dt*16 + lm;
                const float* fb = feat + (size_t)(b*64 + d) * NPTS;
                frag_u B;
                #pragma unroll
                for (int r = 0; r < 4; ++r) {
                    const int k0 = lg*8 + 2*r;
                    B.u[r] = pack_bf16pair(fb[idxs[e][k0]], fb[idxs[e][k0+1]]);
                }
                #pragma unroll
                for (int w4 = 0; w4 < 4; ++w4) {
                    f32x4 dnf = {0.f, 0.f, 0.f, 0.f};
                    dnf = __builtin_amdgcn_mfma_f32_16x16x32_bf16(afr[es][w4].h, B.h, dnf, 0, 0, 0);
                    const unsigned p0 = pack_bf16pair(dnf[0], dnf[1]);
                    const unsigned p1 = pack_bf16pair(dnf[2], dnf[3]);
                    const int dloc = dt*16 + lm;
                    const int kp0 = dloc*32 + w4*8 + lg*2;
                    const int sw = kp0 ^ ((lm & 3) << 3) ^ ((e & 7) << 2);
                    *(uint2*)&yaf[e*1024 + sw] = make_uint2(p0, p1);
                }
            }
        }
        __syncthreads();
        for (int kt = 0; kt < 64; kt += 2) {
            frag_u A0, B0, A1, B1;
            const int kpb0 = (kt*16 + lg*4) ^ (((kt >> 1) & 3) << 3) ^ ((lm & 7) << 2);
            const int kpb1 = ((kt+1)*16 + lg*4) ^ ((((kt+1) >> 1) & 3) << 3) ^ ((lm & 7) << 2);
            A0.u4 = *(const uint4*)&yaf[(lm & 7)*1024 + kpb0];
            A1.u4 = *(const uint4*)&yaf[(lm & 7)*1024 + kpb1];
            B0.u4 = *(const uint4*)&wfb[(((size_t)(dhalf*64 + kt)*4 + wid)*64 + lane)*4];
            B1.u4 = *(const uint4*)&wfb[(((size_t)(dhalf*64 + kt + 1)*4 + wid)*64 + lane)*4];
            yaccA = __builtin_amdgcn_mfma_f32_16x16x32_bf16(A0.h, B0.h, yaccA, 0, 0, 0);
            yaccB = __builtin_amdgcn_mfma_f32_16x16x32_bf16(A1.h, B1.h, yaccB, 0, 0, 0);
        }
        __syncthreads();
    }
    if (lg < 2) {
        const float bfo = bf[wid*16 + lm];
        #pragma unroll
        for (int r = 0; r < 4; ++r)
            y[(size_t)(bs0 + lg*4 + r) * 64 + wid*16 + lm] = (yaccA[r] + yaccB[r]) + bfo;
    }
}

__global__ __launch_bounds__(256) void ystats_kernel(const float* __restrict__ y,
                                                     double* __restrict__ st)
{
    const int tid = threadIdx.x;
    const int c = tid & 63;
    double s = 0.0, s2 = 0.0;
    for (int i = blockIdx.x * 256 + tid; i < NBATCH*NSAMP*64; i += gridDim.x * 256) {
        const float v = y[i];
        s += v; s2 += (double)v * (double)v;
    }
    __shared__ double rs[256], rs2[256];
    rs[tid] = s; rs2[tid] = s2;
    __syncthreads();
    if (tid < 64) {
        const double a  = rs[c]  + rs[64+c]  + rs[128+c]  + rs[192+c];
        const double a2 = rs2[c] + rs2[64+c] + rs2[128+c] + rs2[192+c];
        atomicAdd(&st[c], a);
        atomicAdd(&st[64 + c], a2);
    }
}

__global__ void writeout_kernel(const float* __restrict__ y,
                                const float* __restrict__ bnp3,
                                float* __restrict__ outp)
{
    const int i = blockIdx.x * 256 + threadIdx.x;
    if (i >= NBATCH * 64 * NSAMP) return;
    const int s = i & 1023;
    const int o = (i >> 10) & 63;
    const int bb = i >> 16;
    const float v = y[((size_t)(bb << 10) + s) * 64 + o];
    outp[i] = fmaxf(bnp3[o] * v + bnp3[64 + o], 0.f);
}

// ============================ launch ============================
extern "C" void kernel_launch(void* const* d_in, const int* in_sizes, int n_in,
                              void* d_out, int out_size, void* d_ws, size_t ws_size,
                              hipStream_t stream)
{
    (void)in_sizes; (void)n_in; (void)out_size; (void)ws_size;
    const float* xyz  = (const float*)d_in[0];
    const float* feat = (const float*)d_in[1];
    const float* w0   = (const float*)d_in[2];
    const float* b0   = (const float*)d_in[3];
    const float* g0   = (const float*)d_in[4];
    const float* be0  = (const float*)d_in[5];
    const float* w1   = (const float*)d_in[6];
    const float* b1   = (const float*)d_in[7];
    const float* g1   = (const float*)d_in[8];
    const float* be1  = (const float*)d_in[9];
    const float* w2   = (const float*)d_in[10];
    const float* b2   = (const float*)d_in[11];
    const float* g2   = (const float*)d_in[12];
    const float* be2  = (const float*)d_in[13];
    const float* wf   = (const float*)d_in[14];
    const float* bf   = (const float*)d_in[15];
    const float* gf   = (const float*)d_in[16];
    const float* bef  = (const float*)d_in[17];

    float* out = (float*)d_out;
    float* newxyz = out;                       // (B, S, 3)
    float* outmain = out + NBATCH * NSAMP * 3; // (B, 64, S)

    char* ws = (char*)d_ws;
    int*      idxws = (int*)ws;                            // 2 MB
    float*    ybuf  = (float*)(ws + 2097152);              // 4 MB
    double*   stats = (double*)(ws + 6291456);             // 4 KB
    float*    bnp   = (float*)(ws + 6295552);              // 2 KB
    unsigned* wfb   = (unsigned*)(ws + 6297600);           // 512 KB
    unsigned* w1b   = (unsigned*)(ws + 6821888);           // 8 KB
    unsigned* w2b   = (unsigned*)(ws + 6830080);           // 8 KB
    float*    G1    = (float*)(ws + 6838272);              // 16 KB
    float*    G2    = (float*)(ws + 6854656);              // 16 KB

    zero_all_kernel<<<16, 256, 0, stream>>>(stats, G1, G2);
    wfpack_all_kernel<<<528, 64, 0, stream>>>(wf, w1, w2, wfb, w1b, w2b);
    fps_kernel<<<NBATCH, 256, 0, stream>>>(xyz, newxyz);
    knn_kernel<<<NBATCH * NSAMP, 256, 0, stream>>>(xyz, newxyz, idxws);

    gxmoments_kernel<<<1024, 256, 0, stream>>>(xyz, newxyz, idxws, stats);
    bn0_moments_finalize_kernel<<<1, 64, 0, stream>>>(stats, w0, b0, g0, be0, bnp);
    gram1_kernel<<<256, 256, 0, stream>>>(xyz, newxyz, idxws, w0, b0, bnp, G1, stats + 128);
    bn_gram_finalize_kernel<<<1, 256, 0, stream>>>(stats + 128, G1, w1, b1, g1, be1, bnp + 128);
    gram2_kernel<<<256, 256, 0, stream>>>(xyz, newxyz, idxws, w0, b0, b1, w1b, bnp, G2, stats + 192);
    bn_gram_finalize_kernel<<<1, 256, 0, stream>>>(stats + 192, G2, w2, b2, g2, be2, bnp + 256);

    final_conv_kernel<<<NBATCH * NSAMP / 8, 256, 0, stream>>>(
        xyz, newxyz, idxws, feat, w0, b0, b1, b2, bnp, wfb, w1b, w2b, bf, ybuf);

    ystats_kernel<<<256, 256, 0, stream>>>(ybuf, stats + 384);
    bn_finalize_kernel<<<1, 64, 0, stream>>>(stats + 384, gf, bef, bnp + 384, (float)(NBATCH * NSAMP));
    writeout_kernel<<<4096, 256, 0, stream>>>(ybuf, bnp + 384, outmain);
}

// Round 12
// 1236.150 us; speedup vs baseline: 1.1296x; 1.1296x over previous
//
#include <hip/hip_runtime.h>

#define NBATCH 16
#define NPTS   4096
#define NSAMP  1024
#define NKNN   32
#define NROWS  (NBATCH*NSAMP*NKNN)   // 524288
#define BN_EPS 1e-5f
#define H1PAD  66
#define KNN_CAP 512

typedef __attribute__((ext_vector_type(4))) float f32x4;
typedef __attribute__((ext_vector_type(8))) short bf16x8;
union frag_u { unsigned u[4]; bf16x8 h; uint4 u4; };

__device__ __forceinline__ unsigned pack_bf16pair(float a, float b) {
    unsigned ua = __float_as_uint(a); ua += 0x7FFFu + ((ua >> 16) & 1u);
    unsigned ub = __float_as_uint(b); ub += 0x7FFFu + ((ub >> 16) & 1u);
    return (ua >> 16) | (ub & 0xFFFF0000u);
}
__device__ __forceinline__ unsigned short bf16_rne(float a) {
    unsigned ua = __float_as_uint(a); ua += 0x7FFFu + ((ua >> 16) & 1u);
    return (unsigned short)(ua >> 16);
}

// ============================ FPS v5 ============================
// (validated rounds 1-11; structural latency floor ~650us — untouched)
__global__ __launch_bounds__(256) void fps_kernel(const float* __restrict__ xyz,
                                                  float* __restrict__ newxyz)
{
    const int b = blockIdx.x;
    const int tid = threadIdx.x;
    const int wv = tid >> 6;          // 0..3
    const float* xb = xyz + (size_t)b * NPTS * 3;
    __shared__ float xs[NPTS];
    __shared__ float ys[NPTS];
    __shared__ float zs[NPTS];
    __shared__ __align__(16) float4 red[2][4];   // (maxval, x, y, z)
    __shared__ __align__(16) float nxs[NSAMP*3]; // 12 KB output staging
    float px[16], py[16], pz[16], dmin[16];
    {
        float arr[48];
        const float4* s4 = (const float4*)(xb + (size_t)tid * 48);
        #pragma unroll
        for (int i = 0; i < 12; ++i) *(float4*)&arr[i*4] = s4[i];
        #pragma unroll
        for (int j = 0; j < 16; ++j) {
            px[j] = arr[3*j]; py[j] = arr[3*j+1]; pz[j] = arr[3*j+2];
            const int p = tid * 16 + j;
            xs[p] = px[j]; ys[p] = py[j]; zs[p] = pz[j];
            dmin[j] = 1e10f;
        }
    }
    if (tid == 0) { nxs[0] = xb[0]; nxs[1] = xb[1]; nxs[2] = xb[2]; }
    __syncthreads();
    float lx = xs[0], ly = ys[0], lz = zs[0];
    for (int t = 1; t < NSAMP; ++t) {
        float bv = -1.0f;
        #pragma unroll
        for (int j = 0; j < 16; ++j) {
            const float dx = __fsub_rn(px[j], lx);
            const float dy = __fsub_rn(py[j], ly);
            const float dz = __fsub_rn(pz[j], lz);
            const float d = __fadd_rn(__fadd_rn(__fmul_rn(dx,dx), __fmul_rn(dy,dy)), __fmul_rn(dz,dz));
            const float nd = fminf(dmin[j], d);
            dmin[j] = nd;
            bv = fmaxf(bv, nd);
        }
        int lj = 0;
        #pragma unroll
        for (int j = 15; j >= 0; --j) if (dmin[j] == bv) lj = j;
        const int bi_lane = tid * 16 + lj;
        float mv = bv;
        {
            int s_;
            s_ = __builtin_amdgcn_mov_dpp(__float_as_int(mv), 0x111, 0xf, 0xf, true);
            mv = fmaxf(mv, __int_as_float(s_));
            s_ = __builtin_amdgcn_mov_dpp(__float_as_int(mv), 0x112, 0xf, 0xf, true);
            mv = fmaxf(mv, __int_as_float(s_));
            s_ = __builtin_amdgcn_mov_dpp(__float_as_int(mv), 0x114, 0xf, 0xf, true);
            mv = fmaxf(mv, __int_as_float(s_));
            s_ = __builtin_amdgcn_mov_dpp(__float_as_int(mv), 0x118, 0xf, 0xf, true);
            mv = fmaxf(mv, __int_as_float(s_));
            s_ = __builtin_amdgcn_mov_dpp(__float_as_int(mv), 0x142, 0xf, 0xf, true);
            mv = fmaxf(mv, __int_as_float(s_));
            s_ = __builtin_amdgcn_mov_dpp(__float_as_int(mv), 0x143, 0xf, 0xf, true);
            mv = fmaxf(mv, __int_as_float(s_));
        }
        mv = __int_as_float(__builtin_amdgcn_readlane(__float_as_int(mv), 63));
        const unsigned long long mask = __ballot(bv == mv);
        const int winner = __ffsll(mask) - 1;
        const int bi_w = __builtin_amdgcn_readlane(bi_lane, winner);
        const float wx = xs[bi_w], wy = ys[bi_w], wz = zs[bi_w];
        const int par = t & 1;
        if ((tid & 63) == 0) red[par][wv] = make_float4(mv, wx, wy, wz);
        __syncthreads();
        float4 w0 = red[par][0];
        const float4 w1 = red[par][1];
        const float4 w2 = red[par][2];
        const float4 w3 = red[par][3];
        if (w1.x > w0.x) w0 = w1;
        if (w2.x > w0.x) w0 = w2;
        if (w3.x > w0.x) w0 = w3;
        lx = w0.y; ly = w0.z; lz = w0.w;
        if (tid == 0) { nxs[t*3] = lx; nxs[t*3+1] = ly; nxs[t*3+2] = lz; }
    }
    __syncthreads();
    {
        float4* d4 = (float4*)(newxyz + (size_t)b * NSAMP * 3);
        const float4* s4 = (const float4*)nxs;
        #pragma unroll
        for (int i = tid; i < NSAMP*3/4; i += 256) d4[i] = s4[i];
    }
}

// ============================ kNN v3 ============================
// v2 (validated r10) + ballot-aggregated top-byte histogram (hot-bin LDS
// atomic serialization removed; counts identical).
__device__ __forceinline__ void bin_select(int* hist, int* ctrl, int* wsum,
                                           int tid, int shift)
{
    const int lane = tid & 63, wv = tid >> 6;
    const int cnt = hist[tid];
    const int r = ctrl[1];            // read old r BEFORE the barrier
    int incl = cnt;
    #pragma unroll
    for (int d = 1; d < 64; d <<= 1) {
        const int v = __shfl_up(incl, d);
        if (lane >= d) incl += v;
    }
    if (lane == 63) wsum[wv] = incl;
    __syncthreads();
    int base = 0;
    if (wv > 0) base += wsum[0];
    if (wv > 1) base += wsum[1];
    if (wv > 2) base += wsum[2];
    incl += base;
    const int excl = incl - cnt;
    if (excl < r && r <= incl) {      // exactly one thread
        ctrl[0] |= tid << shift;
        ctrl[1] = r - excl;
        ctrl[2] = cnt;
    }
}

__global__ __launch_bounds__(256) void knn_kernel(const float* __restrict__ xyz,
                                                  const float* __restrict__ newxyz,
                                                  int* __restrict__ idx_out)
{
    const int bs = blockIdx.x;
    const int b = bs >> 10;
    const int tid = threadIdx.x;
    const int lane = tid & 63;
    __shared__ unsigned keys[NPTS];   // 16 KB
    __shared__ int hist[256];
    __shared__ float qsh[3];
    __shared__ int ctrl[8];           // 0:pf 1:r 2:selCnt 3:eqn 4:ltn 5:outn 6:tien
    __shared__ int wsum[4];
    __shared__ int cl[KNN_CAP];
    __shared__ int lt[32];
    __shared__ int ties[128];
    if (tid < 3) qsh[tid] = newxyz[bs*3 + tid];
    if (tid == 0) { ctrl[0] = 0; ctrl[1] = NKNN; }
    hist[tid] = 0;
    __syncthreads();
    const float q0 = qsh[0], q1 = qsh[1], q2 = qsh[2];
    const float qq = __fadd_rn(__fadd_rn(__fmul_rn(q0,q0), __fmul_rn(q1,q1)), __fmul_rn(q2,q2));
    const float* xb = xyz + (size_t)b * NPTS * 3;
    for (int n = tid; n < NPTS; n += 256) {
        const float x0 = xb[n*3+0], x1 = xb[n*3+1], x2 = xb[n*3+2];
        const float xx = __fadd_rn(__fadd_rn(__fmul_rn(x0,x0), __fmul_rn(x1,x1)), __fmul_rn(x2,x2));
        float dt = __fmul_rn(q0, x0);
        dt = __fmaf_rn(q1, x1, dt);
        dt = __fmaf_rn(q2, x2, dt);
        const float dd = __fadd_rn(__fsub_rn(qq, __fmul_rn(2.0f, dt)), xx);
        unsigned ub = __float_as_uint(dd);
        ub = (ub & 0x80000000u) ? ~ub : (ub | 0x80000000u);
        keys[n] = ub;
        // ballot-aggregated histogram add (bins are few & hot)
        const int bin = (int)(ub >> 24);
        unsigned long long act = __ballot(true);
        while (act) {
            const int leader = __ffsll(act) - 1;
            const int lbin = __builtin_amdgcn_readlane(bin, leader);
            const unsigned long long same = __ballot(bin == lbin);
            if (lane == leader) atomicAdd(&hist[lbin], (int)__popcll(same));
            act &= ~same;
        }
    }
    __syncthreads();
    bin_select(hist, ctrl, wsum, tid, 24);
    __syncthreads();
    const unsigned pf3 = (unsigned)ctrl[0];
    const int bin3 = (int)(pf3 >> 24);
    const int m = ctrl[2];
    const bool compact = (m <= KNN_CAP);
    if (tid == 0) { ctrl[3] = 0; ctrl[4] = 0; ctrl[5] = 0; ctrl[6] = 0; }
    __syncthreads();
    if (compact) {
        for (int n = tid; n < NPTS; n += 256) {
            const int tb = (int)(keys[n] >> 24);
            if (tb == bin3)      { const int pos = atomicAdd(&ctrl[3], 1); cl[pos] = n; }
            else if (tb < bin3)  { const int pos = atomicAdd(&ctrl[4], 1); lt[pos] = n; }
        }
    }
    __syncthreads();
    for (int p = 2; p >= 0; --p) {
        hist[tid] = 0;
        __syncthreads();
        const unsigned pre = (unsigned)ctrl[0];
        const int shift = p * 8;
        const unsigned himask = 0xFFFFFFFFu << ((p + 1) * 8);
        if (compact) {
            const int eqn = ctrl[3];
            for (int i = tid; i < eqn; i += 256) {
                const unsigned k = keys[cl[i]];
                if ((k & himask) == pre) atomicAdd(&hist[(k >> shift) & 255], 1);
            }
        } else {
            for (int n = tid; n < NPTS; n += 256) {
                const unsigned k = keys[n];
                if ((k & himask) == pre) atomicAdd(&hist[(k >> shift) & 255], 1);
            }
        }
        __syncthreads();
        bin_select(hist, ctrl, wsum, tid, shift);
        __syncthreads();
    }
    const unsigned T = (unsigned)ctrl[0];
    int* out = idx_out + (size_t)bs * NKNN;
    if (compact) {
        const int ltn = ctrl[4];
        if (tid == 0) ctrl[5] = ltn;
        __syncthreads();
        if (tid < ltn) out[tid] = lt[tid];
        const int eqn = ctrl[3];
        for (int i = tid; i < eqn; i += 256) {
            const int n = cl[i];
            const unsigned k = keys[n];
            if (k < T) {
                const int pos = atomicAdd(&ctrl[5], 1);
                if (pos < NKNN) out[pos] = n;
            } else if (k == T) {
                const int pos = atomicAdd(&ctrl[6], 1);
                if (pos < 128) ties[pos] = n;
            }
        }
    } else {
        for (int n = tid; n < NPTS; n += 256) {
            const unsigned k = keys[n];
            if (k < T) {
                const int pos = atomicAdd(&ctrl[5], 1);
                if (pos < NKNN) out[pos] = n;
            } else if (k == T) {
                const int pos = atomicAdd(&ctrl[6], 1);
                if (pos < 128) ties[pos] = n;
            }
        }
    }
    __syncthreads();
    if (tid == 0) {
        const int nless = ctrl[5] < NKNN ? ctrl[5] : NKNN;
        const int need = NKNN - nless;
        const int ntie = ctrl[6] < 128 ? ctrl[6] : 128;
        int last = -1;
        for (int j = 0; j < need; ++j) {
            int best = 0x7fffffff;
            for (int i = 0; i < ntie; ++i) {
                const int v = ties[i];
                if (v > last && v < best) best = v;
            }
            out[nless + j] = (best == 0x7fffffff) ? 0 : best;
            last = best;
        }
    }
}

// ============================ feat transpose (bf16) ============================
// feat[b][64][4096] f32 -> tfeat[b][4096][64] bf16 (same RNE rounding as
// the former on-the-fly pack). Makes final_conv B-frag loads line-coalesced.
__global__ __launch_bounds__(256) void feat_transpose_kernel(
    const float* __restrict__ feat, unsigned short* __restrict__ tfeat)
{
    __shared__ unsigned short t[64][65];
    const int blk = blockIdx.x;           // 16*64
    const int b = blk >> 6, nt = blk & 63;
    const int tid = threadIdx.x;
    #pragma unroll
    for (int i = 0; i < 16; ++i) {
        const int e = i*256 + tid;
        const int d = e >> 6, n = e & 63;
        t[n][d] = bf16_rne(feat[((size_t)(b*64 + d))*NPTS + nt*64 + n]);
    }
    __syncthreads();
    #pragma unroll
    for (int i = 0; i < 16; ++i) {
        const int e = i*256 + tid;
        const int n = e >> 6, d = e & 63;
        tfeat[((size_t)(b*NPTS) + nt*64 + n)*64 + d] = t[n][d];
    }
}

// ============================ zero / moments ============================
__global__ void zero_all_kernel(double* st, float* g1, float* g2)
{
    const int i = blockIdx.x * 256 + threadIdx.x;
    if (i < 512) st[i] = 0.0;
    if (i < 4096) { g1[i] = 0.f; g2[i] = 0.f; }
}

// f32 partials; also stores gx rows (coalesced) into gxws for reuse by
// gram1/gram2/final_conv Phase A (bits identical to recomputation).
__global__ __launch_bounds__(256) void gxmoments_kernel(
    const float* __restrict__ xyz, const float* __restrict__ newxyz,
    const int* __restrict__ idxws, double* __restrict__ stats,
    float* __restrict__ gxws)
{
    const int tid = threadIdx.x;
    float m[9];
    #pragma unroll
    for (int i = 0; i < 9; ++i) m[i] = 0.f;
    for (int row = blockIdx.x * 256 + tid; row < NROWS; row += gridDim.x * 256) {
        const int bs = row >> 5;
        const int bb = row >> 15;
        const int id = idxws[row];
        const float* xp = xyz + ((size_t)bb * NPTS + id) * 3;
        const float* qp = newxyz + bs * 3;
        const float dx = xp[0] - qp[0];
        const float dy = xp[1] - qp[1];
        const float dz = xp[2] - qp[2];
        gxws[(size_t)row*3 + 0] = dx;
        gxws[(size_t)row*3 + 1] = dy;
        gxws[(size_t)row*3 + 2] = dz;
        m[0] += dx; m[1] += dy; m[2] += dz;
        m[3] += dx*dx; m[4] += dx*dy; m[5] += dx*dz;
        m[6] += dy*dy; m[7] += dy*dz; m[8] += dz*dz;
    }
    double d[9];
    #pragma unroll
    for (int i = 0; i < 9; ++i) {
        d[i] = (double)m[i];
        #pragma unroll
        for (int s = 1; s < 64; s <<= 1) d[i] += __shfl_xor(d[i], s);
    }
    __shared__ double part[4][9];
    if ((tid & 63) == 0) {
        #pragma unroll
        for (int i = 0; i < 9; ++i) part[tid >> 6][i] = d[i];
    }
    __syncthreads();
    if (tid < 9) atomicAdd(&stats[tid], part[0][tid] + part[1][tid] + part[2][tid] + part[3][tid]);
}

__global__ void bn0_moments_finalize_kernel(const double* __restrict__ st,
    const float* __restrict__ w0, const float* __restrict__ b0,
    const float* __restrict__ g0, const float* __restrict__ be0,
    float* __restrict__ outp)
{
    const int c = threadIdx.x;  // 64
    const double N = (double)NROWS;
    const double w0c = w0[c], w1c = w0[64 + c], w2c = w0[128 + c];
    const double b = b0[c];
    const double dotS = st[0]*w0c + st[1]*w1c + st[2]*w2c;
    const double qf = w0c*w0c*st[3] + w1c*w1c*st[6] + w2c*w2c*st[8]
                    + 2.0*(w0c*w1c*st[4] + w0c*w2c*st[5] + w1c*w2c*st[7]);
    const double mean = dotS / N + b;
    const double ex2 = (qf + 2.0*b*dotS) / N + b*b;
    const double var = ex2 - mean*mean;
    const float scale = g0[c] * rsqrtf((float)var + BN_EPS);
    outp[c] = scale;
    outp[64 + c] = be0[c] - (float)mean * scale;
}

// ============================ weight pre-pack (all three in one launch) ====
__global__ void wfpack_all_kernel(const float* __restrict__ wf,
                                  const float* __restrict__ w1,
                                  const float* __restrict__ w2,
                                  unsigned* __restrict__ wfb,
                                  unsigned* __restrict__ w1b,
                                  unsigned* __restrict__ w2b)
{
    int blk = blockIdx.x;            // 0-511: wf, 512-519: w1, 520-527: w2
    const float* src; unsigned* dst;
    if (blk < 512)      { src = wf; dst = wfb; }
    else if (blk < 520) { src = w1; dst = w1b; blk -= 512; }
    else                { src = w2; dst = w2b; blk -= 520; }
    const int kt = blk >> 2, ot = blk & 3;
    const int l = threadIdx.x;            // 64
    const int o = ot*16 + (l & 15);
    const int kb = kt*32 + (l >> 4)*8;
    unsigned out[4];
    #pragma unroll
    for (int r = 0; r < 4; ++r) {
        const float a = src[(size_t)(kb + 2*r) * 64 + o];
        const float b = src[(size_t)(kb + 2*r + 1) * 64 + o];
        out[r] = pack_bf16pair(a, b);
    }
    *(uint4*)&dst[((size_t)blk * 64 + l) * 4] = *(const uint4*)out;
}

// ============================ Gram stats ============================
__global__ __launch_bounds__(256) void gram1_kernel(
    const float* __restrict__ gxws,
    const float* __restrict__ w0, const float* __restrict__ b0,
    const float* __restrict__ bnp, float* __restrict__ G1,
    double* __restrict__ Sh1)
{
    __shared__ float gxs[32][3];
    __shared__ float h1s[32][H1PAD];
    __shared__ float rsum[256];
    const int tid = threadIdx.x;
    const int c = tid & 63;
    const int rq = tid >> 6;
    const int lg = c >> 4, lm = c & 15;
    const float w0c0 = w0[c], w0c1 = w0[64+c], w0c2 = w0[128+c];
    const float b0c = b0[c], sc0 = bnp[c], sh0 = bnp[64+c];
    f32x4 Ga[4] = {{0,0,0,0},{0,0,0,0},{0,0,0,0},{0,0,0,0}};
    float sumh = 0.f;
    for (int chunk = blockIdx.x; chunk < NROWS/32; chunk += gridDim.x) {
        if (tid < 96) ((float*)gxs)[tid] = gxws[(size_t)chunk*96 + tid];
        __syncthreads();
        #pragma unroll
        for (int i = 0; i < 8; ++i) {
            const int r = rq*8 + i;
            const float t0 = gxs[r][0]*w0c0 + gxs[r][1]*w0c1 + gxs[r][2]*w0c2 + b0c;
            const float h = fmaxf(sc0*t0 + sh0, 0.f);
            h1s[r][c] = h;
            sumh += h;
        }
        __syncthreads();
        frag_u fr[4];
        #pragma unroll
        for (int ct = 0; ct < 4; ++ct)
            #pragma unroll
            for (int r = 0; r < 4; ++r)
                fr[ct].u[r] = pack_bf16pair(h1s[lg*8 + 2*r][ct*16 + lm],
                                            h1s[lg*8 + 2*r + 1][ct*16 + lm]);
        #pragma unroll
        for (int ct = 0; ct < 4; ++ct)
            Ga[ct] = __builtin_amdgcn_mfma_f32_16x16x32_bf16(fr[rq].h, fr[ct].h, Ga[ct], 0, 0, 0);
        __syncthreads();
    }
    #pragma unroll
    for (int ct = 0; ct < 4; ++ct)
        #pragma unroll
        for (int r = 0; r < 4; ++r)
            atomicAdd(&G1[(rq*16 + lg*4 + r)*64 + ct*16 + lm], Ga[ct][r]);
    rsum[tid] = sumh;
    __syncthreads();
    if (tid < 64) atomicAdd(&Sh1[c], (double)(rsum[c] + rsum[64+c] + rsum[128+c] + rsum[192+c]));
}

__global__ __launch_bounds__(256) void gram2_kernel(
    const float* __restrict__ gxws,
    const float* __restrict__ w0, const float* __restrict__ b0,
    const float* __restrict__ b1, const unsigned* __restrict__ w1b,
    const float* __restrict__ bnp, float* __restrict__ G2,
    double* __restrict__ Sh2)
{
    __shared__ float gxs[32][3];
    __shared__ float h1s[32][H1PAD];
    __shared__ float h2s[32][H1PAD];
    __shared__ float rsum[256];
    const int tid = threadIdx.x;
    const int c = tid & 63;
    const int rq = tid >> 6;
    const int lg = c >> 4, lm = c & 15;
    const int c2 = rq*16 + lm;
    const float w0c0 = w0[c], w0c1 = w0[64+c], w0c2 = w0[128+c];
    const float b0c = b0[c], sc0 = bnp[c], sh0 = bnp[64+c];
    const float b1c2 = b1[c2], sc1 = bnp[128+c2], sh1 = bnp[192+c2];
    frag_u Bw1[2];
    Bw1[0].u4 = *(const uint4*)&w1b[((0*4 + rq)*64 + c)*4];
    Bw1[1].u4 = *(const uint4*)&w1b[((1*4 + rq)*64 + c)*4];
    f32x4 Ga[4] = {{0,0,0,0},{0,0,0,0},{0,0,0,0},{0,0,0,0}};
    float sumh = 0.f;
    for (int chunk = blockIdx.x; chunk < NROWS/32; chunk += gridDim.x) {
        if (tid < 96) ((float*)gxs)[tid] = gxws[(size_t)chunk*96 + tid];
        __syncthreads();
        #pragma unroll
        for (int i = 0; i < 8; ++i) {
            const int r = rq*8 + i;
            const float t0 = gxs[r][0]*w0c0 + gxs[r][1]*w0c1 + gxs[r][2]*w0c2 + b0c;
            h1s[r][c] = fmaxf(sc0*t0 + sh0, 0.f);
        }
        __syncthreads();
        #pragma unroll
        for (int mt = 0; mt < 2; ++mt) {
            f32x4 acc = {0,0,0,0};
            #pragma unroll
            for (int kt = 0; kt < 2; ++kt) {
                frag_u a;
                #pragma unroll
                for (int r = 0; r < 4; ++r) {
                    const float2 f = *(const float2*)&h1s[mt*16 + lm][kt*32 + lg*8 + 2*r];
                    a.u[r] = pack_bf16pair(f.x, f.y);
                }
                acc = __builtin_amdgcn_mfma_f32_16x16x32_bf16(a.h, Bw1[kt].h, acc, 0, 0, 0);
            }
            #pragma unroll
            for (int r = 0; r < 4; ++r)
                h2s[mt*16 + lg*4 + r][c2] = fmaxf(sc1*(acc[r] + b1c2) + sh1, 0.f);
        }
        __syncthreads();
        #pragma unroll
        for (int i = 0; i < 8; ++i) sumh += h2s[rq*8 + i][c];
        frag_u fr[4];
        #pragma unroll
        for (int ct = 0; ct < 4; ++ct)
            #pragma unroll
            for (int r = 0; r < 4; ++r)
                fr[ct].u[r] = pack_bf16pair(h2s[lg*8 + 2*r][ct*16 + lm],
                                            h2s[lg*8 + 2*r + 1][ct*16 + lm]);
        #pragma unroll
        for (int ct = 0; ct < 4; ++ct)
            Ga[ct] = __builtin_amdgcn_mfma_f32_16x16x32_bf16(fr[rq].h, fr[ct].h, Ga[ct], 0, 0, 0);
        __syncthreads();
    }
    #pragma unroll
    for (int ct = 0; ct < 4; ++ct)
        #pragma unroll
        for (int r = 0; r < 4; ++r)
            atomicAdd(&G2[(rq*16 + lg*4 + r)*64 + ct*16 + lm], Ga[ct][r]);
    rsum[tid] = sumh;
    __syncthreads();
    if (tid < 64) atomicAdd(&Sh2[c], (double)(rsum[c] + rsum[64+c] + rsum[128+c] + rsum[192+c]));
}

__global__ __launch_bounds__(256) void bn_gram_finalize_kernel(
    const double* __restrict__ Sh, const float* __restrict__ G,
    const float* __restrict__ w, const float* __restrict__ bias,
    const float* __restrict__ g, const float* __restrict__ be,
    float* __restrict__ outp)
{
    __shared__ float wls[64][65];
    __shared__ double shl[64];
    __shared__ double rd[256], rqd[256];
    const int tid = threadIdx.x;
    const int c = tid & 63;
    const int rqi = tid >> 6;
    for (int i = tid; i < 4096; i += 256) wls[i >> 6][i & 63] = w[i];
    if (tid < 64) shl[tid] = Sh[tid];
    __syncthreads();
    double dot = 0.0, quad = 0.0;
    for (int j = rqi*16; j < rqi*16 + 16; ++j) {
        const double wjc = (double)wls[j][c];
        dot += wjc * shl[j];
        double inner = 0.0;
        for (int k = 0; k < 64; ++k) inner += (double)G[j*64 + k] * (double)wls[k][c];
        quad += wjc * inner;
    }
    rd[tid] = dot; rqd[tid] = quad;
    __syncthreads();
    if (tid < 64) {
        const double d = rd[c] + rd[64+c] + rd[128+c] + rd[192+c];
        const double q = rqd[c] + rqd[64+c] + rqd[128+c] + rqd[192+c];
        const double N = (double)NROWS;
        const double bc = (double)bias[c];
        const double mean = d / N + bc;
        const double ex2 = (q + 2.0*bc*d) / N + bc*bc;
        const double var = ex2 - mean*mean;
        const float scale = g[c] * rsqrtf((float)var + BN_EPS);
        outp[c] = scale;
        outp[64 + c] = be[c] - (float)mean * scale;
    }
}

__global__ void bn_finalize_kernel(const double* __restrict__ st,
                                   const float* __restrict__ g,
                                   const float* __restrict__ be,
                                   float* __restrict__ outp, float n)
{
    const int c = threadIdx.x;  // 64
    const double m = st[c] / (double)n;
    const double var = st[64 + c] / (double)n - m * m;
    const float scale = g[c] * rsqrtf((float)var + BN_EPS);
    outp[c] = scale;
    outp[64 + c] = be[c] - (float)m * scale;
}

// ============================ final fused conv ============================
// r12: gx from gxws (coalesced); Phase B feat gathers from bf16-transposed
// tfeat (16-lane line-coalesced u16 loads). Numerics identical.
__global__ __launch_bounds__(256) void final_conv_kernel(
    const float* __restrict__ gxws,
    const int* __restrict__ idxws, const unsigned short* __restrict__ tfeat,
    const float* __restrict__ w0, const float* __restrict__ b0,
    const float* __restrict__ b1, const float* __restrict__ b2,
    const float* __restrict__ bnp, const unsigned* __restrict__ wfb,
    const unsigned* __restrict__ w1b, const unsigned* __restrict__ w2b,
    const float* __restrict__ bf, float* __restrict__ y)
{
    __shared__ unsigned wtp[8][16][64];
    __shared__ __align__(16) float scratch[2*64*H1PAD];
    __shared__ float gxs[256][3];
    __shared__ int   idxs[8][32];
    float* h1s = scratch;
    float* h2s = scratch + 64*H1PAD;
    unsigned* yaf = (unsigned*)scratch;
    const int tid = threadIdx.x;
    const int c = tid & 63;
    const int rq = tid >> 6;
    const int lg = c >> 4, lm = c & 15;
    const int c2 = rq*16 + lm;
    const int bs0 = blockIdx.x * 8;
    const int b = bs0 >> 10;
    idxs[tid >> 5][tid & 31] = idxws[(size_t)bs0 * NKNN + tid];
    const float w0c0 = w0[c], w0c1 = w0[64+c], w0c2 = w0[128+c];
    const float b0c = b0[c], sc0 = bnp[c], sh0 = bnp[64+c];
    const float b1c2 = b1[c2], sc1 = bnp[128+c2], sh1 = bnp[192+c2];
    const float b2c2 = b2[c2], sc2 = bnp[256+c2], sh2 = bnp[320+c2];
    frag_u Bw1[2], Bw2[2];
    #pragma unroll
    for (int kt = 0; kt < 2; ++kt) {
        Bw1[kt].u4 = *(const uint4*)&w1b[((kt*4 + rq)*64 + c)*4];
        Bw2[kt].u4 = *(const uint4*)&w2b[((kt*4 + rq)*64 + c)*4];
    }
    // block's 256 gx rows are contiguous in gxws: rows [bs0*32, bs0*32+256)
    for (int i = tid; i < 768; i += 256)
        ((float*)gxs)[i] = gxws[(size_t)bs0*96 + i];
    __syncthreads();
    for (int chunk = 0; chunk < 4; ++chunk) {
        #pragma unroll
        for (int i = 0; i < 16; ++i) {
            const int r = rq*16 + i;
            const int gr = chunk*64 + r;
            const float t0 = gxs[gr][0]*w0c0 + gxs[gr][1]*w0c1 + gxs[gr][2]*w0c2 + b0c;
            h1s[r*H1PAD + c] = fmaxf(sc0*t0 + sh0, 0.f);
        }
        __syncthreads();
        #pragma unroll
        for (int mt = 0; mt < 4; ++mt) {
            f32x4 acc = {0,0,0,0};
            #pragma unroll
            for (int kt = 0; kt < 2; ++kt) {
                frag_u a;
                #pragma unroll
                for (int r = 0; r < 4; ++r) {
                    const float2 f = *(const float2*)&h1s[(mt*16 + lm)*H1PAD + kt*32 + lg*8 + 2*r];
                    a.u[r] = pack_bf16pair(f.x, f.y);
                }
                acc = __builtin_amdgcn_mfma_f32_16x16x32_bf16(a.h, Bw1[kt].h, acc, 0, 0, 0);
            }
            #pragma unroll
            for (int r = 0; r < 4; ++r)
                h2s[(mt*16 + lg*4 + r)*H1PAD + c2] = fmaxf(sc1*(acc[r] + b1c2) + sh1, 0.f);
        }
        __syncthreads();
        #pragma unroll
        for (int mt = 0; mt < 4; ++mt) {
            f32x4 acc = {0,0,0,0};
            #pragma unroll
            for (int kt = 0; kt < 2; ++kt) {
                frag_u a;
                #pragma unroll
                for (int r = 0; r < 4; ++r) {
                    const float2 f = *(const float2*)&h2s[(mt*16 + lm)*H1PAD + kt*32 + lg*8 + 2*r];
                    a.u[r] = pack_bf16pair(f.x, f.y);
                }
                acc = __builtin_amdgcn_mfma_f32_16x16x32_bf16(a.h, Bw2[kt].h, acc, 0, 0, 0);
            }
            float wt[4];
            #pragma unroll
            for (int r = 0; r < 4; ++r)
                wt[r] = fmaxf(sc2*(acc[r] + b2c2) + sh2, 0.f);
            const int grow0 = chunk*64 + mt*16 + lg*4;
            const int e = grow0 >> 5, kl = grow0 & 31;
            wtp[e][kl >> 1][c2]       = pack_bf16pair(wt[0], wt[1]);
            wtp[e][(kl >> 1) + 1][c2] = pack_bf16pair(wt[2], wt[3]);
        }
        __syncthreads();
    }
    const int lane = c;
    const int wid = rq;
    frag_u afr[2][4];
    #pragma unroll
    for (int es = 0; es < 2; ++es)
        #pragma unroll
        for (int w4 = 0; w4 < 4; ++w4)
            #pragma unroll
            for (int r = 0; r < 4; ++r)
                afr[es][w4].u[r] = wtp[wid*2 + es][lg*4 + r][w4*16 + lm];
    f32x4 yaccA = {0.f, 0.f, 0.f, 0.f};
    f32x4 yaccB = {0.f, 0.f, 0.f, 0.f};
    const unsigned short* tfb = tfeat + (size_t)b * NPTS * 64;
    for (int dhalf = 0; dhalf < 2; ++dhalf) {
        #pragma unroll
        for (int es = 0; es < 2; ++es) {
            const int e = wid*2 + es;
            #pragma unroll
            for (int dt = 0; dt < 2; ++dt) {
                const int d = dhalf*32 + dt*16 + lm;
                frag_u B;
                #pragma unroll
                for (int r = 0; r < 4; ++r) {
                    const int k0 = lg*8 + 2*r;
                    const unsigned va = tfb[(size_t)idxs[e][k0]   * 64 + d];
                    const unsigned vb = tfb[(size_t)idxs[e][k0+1] * 64 + d];
                    B.u[r] = va | (vb << 16);
                }
                #pragma unroll
                for (int w4 = 0; w4 < 4; ++w4) {
                    f32x4 dnf = {0.f, 0.f, 0.f, 0.f};
                    dnf = __builtin_amdgcn_mfma_f32_16x16x32_bf16(afr[es][w4].h, B.h, dnf, 0, 0, 0);
                    const unsigned p0 = pack_bf16pair(dnf[0], dnf[1]);
                    const unsigned p1 = pack_bf16pair(dnf[2], dnf[3]);
                    const int dloc = dt*16 + lm;
                    const int kp0 = dloc*32 + w4*8 + lg*2;
                    const int sw = kp0 ^ ((lm & 3) << 3) ^ ((e & 7) << 2);
                    *(uint2*)&yaf[e*1024 + sw] = make_uint2(p0, p1);
                }
            }
        }
        __syncthreads();
        for (int kt = 0; kt < 64; kt += 2) {
            frag_u A0, B0, A1, B1;
            const int kpb0 = (kt*16 + lg*4) ^ (((kt >> 1) & 3) << 3) ^ ((lm & 7) << 2);
            const int kpb1 = ((kt+1)*16 + lg*4) ^ ((((kt+1) >> 1) & 3) << 3) ^ ((lm & 7) << 2);
            A0.u4 = *(const uint4*)&yaf[(lm & 7)*1024 + kpb0];
            A1.u4 = *(const uint4*)&yaf[(lm & 7)*1024 + kpb1];
            B0.u4 = *(const uint4*)&wfb[(((size_t)(dhalf*64 + kt)*4 + wid)*64 + lane)*4];
            B1.u4 = *(const uint4*)&wfb[(((size_t)(dhalf*64 + kt + 1)*4 + wid)*64 + lane)*4];
            yaccA = __builtin_amdgcn_mfma_f32_16x16x32_bf16(A0.h, B0.h, yaccA, 0, 0, 0);
            yaccB = __builtin_amdgcn_mfma_f32_16x16x32_bf16(A1.h, B1.h, yaccB, 0, 0, 0);
        }
        __syncthreads();
    }
    if (lg < 2) {
        const float bfo = bf[wid*16 + lm];
        #pragma unroll
        for (int r = 0; r < 4; ++r)
            y[(size_t)(bs0 + lg*4 + r) * 64 + wid*16 + lm] = (yaccA[r] + yaccB[r]) + bfo;
    }
}

__global__ __launch_bounds__(256) void ystats_kernel(const float* __restrict__ y,
                                                     double* __restrict__ st)
{
    const int tid = threadIdx.x;
    const int c = tid & 63;
    double s = 0.0, s2 = 0.0;
    for (int i = blockIdx.x * 256 + tid; i < NBATCH*NSAMP*64; i += gridDim.x * 256) {
        const float v = y[i];
        s += v; s2 += (double)v * (double)v;
    }
    __shared__ double rs[256], rs2[256];
    rs[tid] = s; rs2[tid] = s2;
    __syncthreads();
    if (tid < 64) {
        const double a  = rs[c]  + rs[64+c]  + rs[128+c]  + rs[192+c];
        const double a2 = rs2[c] + rs2[64+c] + rs2[128+c] + rs2[192+c];
        atomicAdd(&st[c], a);
        atomicAdd(&st[64 + c], a2);
    }
}

__global__ void writeout_kernel(const float* __restrict__ y,
                                const float* __restrict__ bnp3,
                                float* __restrict__ outp)
{
    const int i = blockIdx.x * 256 + threadIdx.x;
    if (i >= NBATCH * 64 * NSAMP) return;
    const int s = i & 1023;
    const int o = (i >> 10) & 63;
    const int bb = i >> 16;
    const float v = y[((size_t)(bb << 10) + s) * 64 + o];
    outp[i] = fmaxf(bnp3[o] * v + bnp3[64 + o], 0.f);
}

// ============================ launch ============================
extern "C" void kernel_launch(void* const* d_in, const int* in_sizes, int n_in,
                              void* d_out, int out_size, void* d_ws, size_t ws_size,
                              hipStream_t stream)
{
    (void)in_sizes; (void)n_in; (void)out_size; (void)ws_size;
    const float* xyz  = (const float*)d_in[0];
    const float* feat = (const float*)d_in[1];
    const float* w0   = (const float*)d_in[2];
    const float* b0   = (const float*)d_in[3];
    const float* g0   = (const float*)d_in[4];
    const float* be0  = (const float*)d_in[5];
    const float* w1   = (const float*)d_in[6];
    const float* b1   = (const float*)d_in[7];
    const float* g1   = (const float*)d_in[8];
    const float* be1  = (const float*)d_in[9];
    const float* w2   = (const float*)d_in[10];
    const float* b2   = (const float*)d_in[11];
    const float* g2   = (const float*)d_in[12];
    const float* be2  = (const float*)d_in[13];
    const float* wf   = (const float*)d_in[14];
    const float* bf   = (const float*)d_in[15];
    const float* gf   = (const float*)d_in[16];
    const float* bef  = (const float*)d_in[17];

    float* out = (float*)d_out;
    float* newxyz = out;                       // (B, S, 3)
    float* outmain = out + NBATCH * NSAMP * 3; // (B, 64, S)

    char* ws = (char*)d_ws;
    int*      idxws = (int*)ws;                            // 2 MB
    float*    ybuf  = (float*)(ws + 2097152);              // 4 MB
    double*   stats = (double*)(ws + 6291456);             // 4 KB
    float*    bnp   = (float*)(ws + 6295552);              // 2 KB
    unsigned* wfb   = (unsigned*)(ws + 6297600);           // 512 KB
    unsigned* w1b   = (unsigned*)(ws + 6821888);           // 8 KB
    unsigned* w2b   = (unsigned*)(ws + 6830080);           // 8 KB
    float*    G1    = (float*)(ws + 6838272);              // 16 KB
    float*    G2    = (float*)(ws + 6854656);              // 16 KB
    float*    gxws  = (float*)(ws + 6871040);              // 6 MB (NROWS*12B)
    unsigned short* tfeat = (unsigned short*)(ws + 13164544); // 8 MB

    zero_all_kernel<<<16, 256, 0, stream>>>(stats, G1, G2);
    wfpack_all_kernel<<<528, 64, 0, stream>>>(wf, w1, w2, wfb, w1b, w2b);
    feat_transpose_kernel<<<1024, 256, 0, stream>>>(feat, tfeat);
    fps_kernel<<<NBATCH, 256, 0, stream>>>(xyz, newxyz);
    knn_kernel<<<NBATCH * NSAMP, 256, 0, stream>>>(xyz, newxyz, idxws);

    gxmoments_kernel<<<1024, 256, 0, stream>>>(xyz, newxyz, idxws, stats, gxws);
    bn0_moments_finalize_kernel<<<1, 64, 0, stream>>>(stats, w0, b0, g0, be0, bnp);
    gram1_kernel<<<256, 256, 0, stream>>>(gxws, w0, b0, bnp, G1, stats + 128);
    bn_gram_finalize_kernel<<<1, 256, 0, stream>>>(stats + 128, G1, w1, b1, g1, be1, bnp + 128);
    gram2_kernel<<<256, 256, 0, stream>>>(gxws, w0, b0, b1, w1b, bnp, G2, stats + 192);
    bn_gram_finalize_kernel<<<1, 256, 0, stream>>>(stats + 192, G2, w2, b2, g2, be2, bnp + 256);

    final_conv_kernel<<<NBATCH * NSAMP / 8, 256, 0, stream>>>(
        gxws, idxws, tfeat, w0, b0, b1, b2, bnp, wfb, w1b, w2b, bf, ybuf);

    ystats_kernel<<<256, 256, 0, stream>>>(ybuf, stats + 384);
    bn_finalize_kernel<<<1, 64, 0, stream>>>(stats + 384, gf, bef, bnp + 384, (float)(NBATCH * NSAMP));
    writeout_kernel<<<4096, 256, 0, stream>>>(ybuf, bnp + 384, outmain);
}

// Round 13
// 1231.116 us; speedup vs baseline: 1.1342x; 1.0041x over previous
//
#include <hip/hip_runtime.h>

#define NBATCH 16
#define NPTS   4096
#define NSAMP  1024
#define NKNN   32
#define NROWS  (NBATCH*NSAMP*NKNN)   // 524288
#define BN_EPS 1e-5f
#define H1PAD  66
#define KNN_CAP 512

typedef __attribute__((ext_vector_type(4))) float f32x4;
typedef __attribute__((ext_vector_type(8))) short bf16x8;
union frag_u { unsigned u[4]; bf16x8 h; uint4 u4; };

__device__ __forceinline__ unsigned pack_bf16pair(float a, float b) {
    unsigned ua = __float_as_uint(a); ua += 0x7FFFu + ((ua >> 16) & 1u);
    unsigned ub = __float_as_uint(b); ub += 0x7FFFu + ((ub >> 16) & 1u);
    return (ua >> 16) | (ub & 0xFFFF0000u);
}
__device__ __forceinline__ unsigned short bf16_rne(float a) {
    unsigned ua = __float_as_uint(a); ua += 0x7FFFu + ((ua >> 16) & 1u);
    return (unsigned short)(ua >> 16);
}

// ============================ prep (fps + transpose + wfpack + zero) =======
// Role by blockIdx: [0,16) fps (dispatched first, owns its CUs for ~650us);
// [16,1040) feat transpose; [1040,1172) weight pre-pack; [1172,1188) zero.
// The independent prep roles fill the 240 idle CUs during fps -> their
// serial launch time disappears. fps body identical to rounds 5-12.
union PrepLds {
    struct {
        float xs[NPTS]; float ys[NPTS]; float zs[NPTS];
        float4 red[2][4];
        float nxs[NSAMP*3];
    } f;
    unsigned short tt[64][65];
};

__global__ __launch_bounds__(256) void prep_kernel(
    const float* __restrict__ xyz, float* __restrict__ newxyz,
    const float* __restrict__ feat, unsigned short* __restrict__ tfeat,
    const float* __restrict__ wf, const float* __restrict__ w1,
    const float* __restrict__ w2, unsigned* __restrict__ wfb,
    unsigned* __restrict__ w1b, unsigned* __restrict__ w2b,
    double* __restrict__ st, float* __restrict__ g1f, float* __restrict__ g2f)
{
    __shared__ PrepLds L;
    const int blk = blockIdx.x;
    const int tid = threadIdx.x;
    if (blk >= 1172) {               // ---- zero role ----
        const int i = (blk - 1172) * 256 + tid;
        if (i < 512) st[i] = 0.0;
        if (i < 4096) { g1f[i] = 0.f; g2f[i] = 0.f; }
        return;
    }
    if (blk >= 1040) {               // ---- wfpack role (4 units/block) ----
        const int unit = (blk - 1040) * 4 + (tid >> 6);
        const int l = tid & 63;
        int u = unit;
        const float* src; unsigned* dst;
        if (u < 512)      { src = wf; dst = wfb; }
        else if (u < 520) { src = w1; dst = w1b; u -= 512; }
        else              { src = w2; dst = w2b; u -= 520; }
        const int kt = u >> 2, ot = u & 3;
        const int o = ot*16 + (l & 15);
        const int kb = kt*32 + (l >> 4)*8;
        unsigned outp[4];
        #pragma unroll
        for (int r = 0; r < 4; ++r) {
            const float a = src[(size_t)(kb + 2*r) * 64 + o];
            const float b = src[(size_t)(kb + 2*r + 1) * 64 + o];
            outp[r] = pack_bf16pair(a, b);
        }
        *(uint4*)&dst[((size_t)u * 64 + l) * 4] = *(const uint4*)outp;
        return;
    }
    if (blk >= 16) {                 // ---- feat transpose role ----
        const int t = blk - 16;       // 0..1023
        const int b = t >> 6, nt = t & 63;
        #pragma unroll
        for (int i = 0; i < 16; ++i) {
            const int e = i*256 + tid;
            const int d = e >> 6, n = e & 63;
            L.tt[n][d] = bf16_rne(feat[((size_t)(b*64 + d))*NPTS + nt*64 + n]);
        }
        __syncthreads();
        #pragma unroll
        for (int i = 0; i < 16; ++i) {
            const int e = i*256 + tid;
            const int n = e >> 6, d = e & 63;
            tfeat[((size_t)(b*NPTS) + nt*64 + n)*64 + d] = L.tt[n][d];
        }
        return;
    }
    // ---- fps role (blocks 0-15; body validated rounds 5-12) ----
    const int b = blk;
    const int wv = tid >> 6;
    const float* xb = xyz + (size_t)b * NPTS * 3;
    float px[16], py[16], pz[16], dmin[16];
    {
        float arr[48];
        const float4* s4 = (const float4*)(xb + (size_t)tid * 48);
        #pragma unroll
        for (int i = 0; i < 12; ++i) *(float4*)&arr[i*4] = s4[i];
        #pragma unroll
        for (int j = 0; j < 16; ++j) {
            px[j] = arr[3*j]; py[j] = arr[3*j+1]; pz[j] = arr[3*j+2];
            const int p = tid * 16 + j;
            L.f.xs[p] = px[j]; L.f.ys[p] = py[j]; L.f.zs[p] = pz[j];
            dmin[j] = 1e10f;
        }
    }
    if (tid == 0) { L.f.nxs[0] = xb[0]; L.f.nxs[1] = xb[1]; L.f.nxs[2] = xb[2]; }
    __syncthreads();
    float lx = L.f.xs[0], ly = L.f.ys[0], lz = L.f.zs[0];
    for (int t = 1; t < NSAMP; ++t) {
        float bv = -1.0f;
        #pragma unroll
        for (int j = 0; j < 16; ++j) {
            const float dx = __fsub_rn(px[j], lx);
            const float dy = __fsub_rn(py[j], ly);
            const float dz = __fsub_rn(pz[j], lz);
            const float d = __fadd_rn(__fadd_rn(__fmul_rn(dx,dx), __fmul_rn(dy,dy)), __fmul_rn(dz,dz));
            const float nd = fminf(dmin[j], d);
            dmin[j] = nd;
            bv = fmaxf(bv, nd);
        }
        int lj = 0;
        #pragma unroll
        for (int j = 15; j >= 0; --j) if (dmin[j] == bv) lj = j;
        const int bi_lane = tid * 16 + lj;
        float mv = bv;
        {
            int s_;
            s_ = __builtin_amdgcn_mov_dpp(__float_as_int(mv), 0x111, 0xf, 0xf, true);
            mv = fmaxf(mv, __int_as_float(s_));
            s_ = __builtin_amdgcn_mov_dpp(__float_as_int(mv), 0x112, 0xf, 0xf, true);
            mv = fmaxf(mv, __int_as_float(s_));
            s_ = __builtin_amdgcn_mov_dpp(__float_as_int(mv), 0x114, 0xf, 0xf, true);
            mv = fmaxf(mv, __int_as_float(s_));
            s_ = __builtin_amdgcn_mov_dpp(__float_as_int(mv), 0x118, 0xf, 0xf, true);
            mv = fmaxf(mv, __int_as_float(s_));
            s_ = __builtin_amdgcn_mov_dpp(__float_as_int(mv), 0x142, 0xf, 0xf, true);
            mv = fmaxf(mv, __int_as_float(s_));
            s_ = __builtin_amdgcn_mov_dpp(__float_as_int(mv), 0x143, 0xf, 0xf, true);
            mv = fmaxf(mv, __int_as_float(s_));
        }
        mv = __int_as_float(__builtin_amdgcn_readlane(__float_as_int(mv), 63));
        const unsigned long long mask = __ballot(bv == mv);
        const int winner = __ffsll(mask) - 1;
        const int bi_w = __builtin_amdgcn_readlane(bi_lane, winner);
        const float wx = L.f.xs[bi_w], wy = L.f.ys[bi_w], wz = L.f.zs[bi_w];
        const int par = t & 1;
        if ((tid & 63) == 0) L.f.red[par][wv] = make_float4(mv, wx, wy, wz);
        __syncthreads();
        float4 w0 = L.f.red[par][0];
        const float4 w1v = L.f.red[par][1];
        const float4 w2v = L.f.red[par][2];
        const float4 w3v = L.f.red[par][3];
        if (w1v.x > w0.x) w0 = w1v;
        if (w2v.x > w0.x) w0 = w2v;
        if (w3v.x > w0.x) w0 = w3v;
        lx = w0.y; ly = w0.z; lz = w0.w;
        if (tid == 0) { L.f.nxs[t*3] = lx; L.f.nxs[t*3+1] = ly; L.f.nxs[t*3+2] = lz; }
    }
    __syncthreads();
    {
        float4* d4 = (float4*)(newxyz + (size_t)b * NSAMP * 3);
        const float4* s4 = (const float4*)L.f.nxs;
        #pragma unroll
        for (int i = tid; i < NSAMP*3/4; i += 256) d4[i] = s4[i];
    }
}

// ============================ kNN v4 ============================
// v3 (validated r10/r12) + output staged in LDS (outl) and, once final,
// the block also emits its 32 gx rows into gxws (xyz warm in L1; same f32
// subtract as before — bits identical). Eliminates gxmoments' re-gather.
__device__ __forceinline__ void bin_select(int* hist, int* ctrl, int* wsum,
                                           int tid, int shift)
{
    const int lane = tid & 63, wv = tid >> 6;
    const int cnt = hist[tid];
    const int r = ctrl[1];            // read old r BEFORE the barrier
    int incl = cnt;
    #pragma unroll
    for (int d = 1; d < 64; d <<= 1) {
        const int v = __shfl_up(incl, d);
        if (lane >= d) incl += v;
    }
    if (lane == 63) wsum[wv] = incl;
    __syncthreads();
    int base = 0;
    if (wv > 0) base += wsum[0];
    if (wv > 1) base += wsum[1];
    if (wv > 2) base += wsum[2];
    incl += base;
    const int excl = incl - cnt;
    if (excl < r && r <= incl) {      // exactly one thread
        ctrl[0] |= tid << shift;
        ctrl[1] = r - excl;
        ctrl[2] = cnt;
    }
}

__global__ __launch_bounds__(256) void knn_kernel(const float* __restrict__ xyz,
                                                  const float* __restrict__ newxyz,
                                                  int* __restrict__ idx_out,
                                                  float* __restrict__ gxws)
{
    const int bs = blockIdx.x;
    const int b = bs >> 10;
    const int tid = threadIdx.x;
    const int lane = tid & 63;
    __shared__ unsigned keys[NPTS];   // 16 KB
    __shared__ int hist[256];
    __shared__ float qsh[3];
    __shared__ int ctrl[8];
    __shared__ int wsum[4];
    __shared__ int cl[KNN_CAP];
    __shared__ int lt[32];
    __shared__ int ties[128];
    __shared__ int outl[NKNN];
    if (tid < 3) qsh[tid] = newxyz[bs*3 + tid];
    if (tid == 0) { ctrl[0] = 0; ctrl[1] = NKNN; }
    hist[tid] = 0;
    __syncthreads();
    const float q0 = qsh[0], q1 = qsh[1], q2 = qsh[2];
    const float qq = __fadd_rn(__fadd_rn(__fmul_rn(q0,q0), __fmul_rn(q1,q1)), __fmul_rn(q2,q2));
    const float* xb = xyz + (size_t)b * NPTS * 3;
    for (int n = tid; n < NPTS; n += 256) {
        const float x0 = xb[n*3+0], x1 = xb[n*3+1], x2 = xb[n*3+2];
        const float xx = __fadd_rn(__fadd_rn(__fmul_rn(x0,x0), __fmul_rn(x1,x1)), __fmul_rn(x2,x2));
        float dt = __fmul_rn(q0, x0);
        dt = __fmaf_rn(q1, x1, dt);
        dt = __fmaf_rn(q2, x2, dt);
        const float dd = __fadd_rn(__fsub_rn(qq, __fmul_rn(2.0f, dt)), xx);
        unsigned ub = __float_as_uint(dd);
        ub = (ub & 0x80000000u) ? ~ub : (ub | 0x80000000u);
        keys[n] = ub;
        const int bin = (int)(ub >> 24);
        unsigned long long act = __ballot(true);
        while (act) {
            const int leader = __ffsll(act) - 1;
            const int lbin = __builtin_amdgcn_readlane(bin, leader);
            const unsigned long long same = __ballot(bin == lbin);
            if (lane == leader) atomicAdd(&hist[lbin], (int)__popcll(same));
            act &= ~same;
        }
    }
    __syncthreads();
    bin_select(hist, ctrl, wsum, tid, 24);
    __syncthreads();
    const unsigned pf3 = (unsigned)ctrl[0];
    const int bin3 = (int)(pf3 >> 24);
    const int m = ctrl[2];
    const bool compact = (m <= KNN_CAP);
    if (tid == 0) { ctrl[3] = 0; ctrl[4] = 0; ctrl[5] = 0; ctrl[6] = 0; }
    __syncthreads();
    if (compact) {
        for (int n = tid; n < NPTS; n += 256) {
            const int tb = (int)(keys[n] >> 24);
            if (tb == bin3)      { const int pos = atomicAdd(&ctrl[3], 1); cl[pos] = n; }
            else if (tb < bin3)  { const int pos = atomicAdd(&ctrl[4], 1); lt[pos] = n; }
        }
    }
    __syncthreads();
    for (int p = 2; p >= 0; --p) {
        hist[tid] = 0;
        __syncthreads();
        const unsigned pre = (unsigned)ctrl[0];
        const int shift = p * 8;
        const unsigned himask = 0xFFFFFFFFu << ((p + 1) * 8);
        if (compact) {
            const int eqn = ctrl[3];
            for (int i = tid; i < eqn; i += 256) {
                const unsigned k = keys[cl[i]];
                if ((k & himask) == pre) atomicAdd(&hist[(k >> shift) & 255], 1);
            }
        } else {
            for (int n = tid; n < NPTS; n += 256) {
                const unsigned k = keys[n];
                if ((k & himask) == pre) atomicAdd(&hist[(k >> shift) & 255], 1);
            }
        }
        __syncthreads();
        bin_select(hist, ctrl, wsum, tid, shift);
        __syncthreads();
    }
    const unsigned T = (unsigned)ctrl[0];
    if (compact) {
        const int ltn = ctrl[4];
        if (tid == 0) ctrl[5] = ltn;
        __syncthreads();
        if (tid < ltn) outl[tid] = lt[tid];
        const int eqn = ctrl[3];
        for (int i = tid; i < eqn; i += 256) {
            const int n = cl[i];
            const unsigned k = keys[n];
            if (k < T) {
                const int pos = atomicAdd(&ctrl[5], 1);
                if (pos < NKNN) outl[pos] = n;
            } else if (k == T) {
                const int pos = atomicAdd(&ctrl[6], 1);
                if (pos < 128) ties[pos] = n;
            }
        }
    } else {
        for (int n = tid; n < NPTS; n += 256) {
            const unsigned k = keys[n];
            if (k < T) {
                const int pos = atomicAdd(&ctrl[5], 1);
                if (pos < NKNN) outl[pos] = n;
            } else if (k == T) {
                const int pos = atomicAdd(&ctrl[6], 1);
                if (pos < 128) ties[pos] = n;
            }
        }
    }
    __syncthreads();
    if (tid == 0) {
        const int nless = ctrl[5] < NKNN ? ctrl[5] : NKNN;
        const int need = NKNN - nless;
        const int ntie = ctrl[6] < 128 ? ctrl[6] : 128;
        int last = -1;
        for (int j = 0; j < need; ++j) {
            int best = 0x7fffffff;
            for (int i = 0; i < ntie; ++i) {
                const int v = ties[i];
                if (v > last && v < best) best = v;
            }
            outl[nless + j] = (best == 0x7fffffff) ? 0 : best;
            last = best;
        }
    }
    __syncthreads();
    if (tid < NKNN) idx_out[(size_t)bs * NKNN + tid] = outl[tid];
    if (tid < 96) {
        const int k = tid / 3, cc = tid % 3;
        gxws[((size_t)bs * NKNN + k) * 3 + cc] = xb[outl[k]*3 + cc] - qsh[cc];
    }
}

// ============================ moments (linear read) ============================
__global__ __launch_bounds__(256) void gxmoments_kernel(
    const float* __restrict__ gxws, double* __restrict__ stats)
{
    const int tid = threadIdx.x;
    float m[9];
    #pragma unroll
    for (int i = 0; i < 9; ++i) m[i] = 0.f;
    for (int row = blockIdx.x * 256 + tid; row < NROWS; row += gridDim.x * 256) {
        const float dx = gxws[(size_t)row*3 + 0];
        const float dy = gxws[(size_t)row*3 + 1];
        const float dz = gxws[(size_t)row*3 + 2];
        m[0] += dx; m[1] += dy; m[2] += dz;
        m[3] += dx*dx; m[4] += dx*dy; m[5] += dx*dz;
        m[6] += dy*dy; m[7] += dy*dz; m[8] += dz*dz;
    }
    double d[9];
    #pragma unroll
    for (int i = 0; i < 9; ++i) {
        d[i] = (double)m[i];
        #pragma unroll
        for (int s = 1; s < 64; s <<= 1) d[i] += __shfl_xor(d[i], s);
    }
    __shared__ double part[4][9];
    if ((tid & 63) == 0) {
        #pragma unroll
        for (int i = 0; i < 9; ++i) part[tid >> 6][i] = d[i];
    }
    __syncthreads();
    if (tid < 9) atomicAdd(&stats[tid], part[0][tid] + part[1][tid] + part[2][tid] + part[3][tid]);
}

__global__ void bn0_moments_finalize_kernel(const double* __restrict__ st,
    const float* __restrict__ w0, const float* __restrict__ b0,
    const float* __restrict__ g0, const float* __restrict__ be0,
    float* __restrict__ outp)
{
    const int c = threadIdx.x;  // 64
    const double N = (double)NROWS;
    const double w0c = w0[c], w1c = w0[64 + c], w2c = w0[128 + c];
    const double b = b0[c];
    const double dotS = st[0]*w0c + st[1]*w1c + st[2]*w2c;
    const double qf = w0c*w0c*st[3] + w1c*w1c*st[6] + w2c*w2c*st[8]
                    + 2.0*(w0c*w1c*st[4] + w0c*w2c*st[5] + w1c*w2c*st[7]);
    const double mean = dotS / N + b;
    const double ex2 = (qf + 2.0*b*dotS) / N + b*b;
    const double var = ex2 - mean*mean;
    const float scale = g0[c] * rsqrtf((float)var + BN_EPS);
    outp[c] = scale;
    outp[64 + c] = be0[c] - (float)mean * scale;
}

// ============================ Gram stats ============================
__global__ __launch_bounds__(256) void gram1_kernel(
    const float* __restrict__ gxws,
    const float* __restrict__ w0, const float* __restrict__ b0,
    const float* __restrict__ bnp, float* __restrict__ G1,
    double* __restrict__ Sh1)
{
    __shared__ float gxs[32][3];
    __shared__ float h1s[32][H1PAD];
    __shared__ float rsum[256];
    const int tid = threadIdx.x;
    const int c = tid & 63;
    const int rq = tid >> 6;
    const int lg = c >> 4, lm = c & 15;
    const float w0c0 = w0[c], w0c1 = w0[64+c], w0c2 = w0[128+c];
    const float b0c = b0[c], sc0 = bnp[c], sh0 = bnp[64+c];
    f32x4 Ga[4] = {{0,0,0,0},{0,0,0,0},{0,0,0,0},{0,0,0,0}};
    float sumh = 0.f;
    for (int chunk = blockIdx.x; chunk < NROWS/32; chunk += gridDim.x) {
        if (tid < 96) ((float*)gxs)[tid] = gxws[(size_t)chunk*96 + tid];
        __syncthreads();
        #pragma unroll
        for (int i = 0; i < 8; ++i) {
            const int r = rq*8 + i;
            const float t0 = gxs[r][0]*w0c0 + gxs[r][1]*w0c1 + gxs[r][2]*w0c2 + b0c;
            const float h = fmaxf(sc0*t0 + sh0, 0.f);
            h1s[r][c] = h;
            sumh += h;
        }
        __syncthreads();
        frag_u fr[4];
        #pragma unroll
        for (int ct = 0; ct < 4; ++ct)
            #pragma unroll
            for (int r = 0; r < 4; ++r)
                fr[ct].u[r] = pack_bf16pair(h1s[lg*8 + 2*r][ct*16 + lm],
                                            h1s[lg*8 + 2*r + 1][ct*16 + lm]);
        #pragma unroll
        for (int ct = 0; ct < 4; ++ct)
            Ga[ct] = __builtin_amdgcn_mfma_f32_16x16x32_bf16(fr[rq].h, fr[ct].h, Ga[ct], 0, 0, 0);
        __syncthreads();
    }
    #pragma unroll
    for (int ct = 0; ct < 4; ++ct)
        #pragma unroll
        for (int r = 0; r < 4; ++r)
            atomicAdd(&G1[(rq*16 + lg*4 + r)*64 + ct*16 + lm], Ga[ct][r]);
    rsum[tid] = sumh;
    __syncthreads();
    if (tid < 64) atomicAdd(&Sh1[c], (double)(rsum[c] + rsum[64+c] + rsum[128+c] + rsum[192+c]));
}

__global__ __launch_bounds__(256) void gram2_kernel(
    const float* __restrict__ gxws,
    const float* __restrict__ w0, const float* __restrict__ b0,
    const float* __restrict__ b1, const unsigned* __restrict__ w1b,
    const float* __restrict__ bnp, float* __restrict__ G2,
    double* __restrict__ Sh2)
{
    __shared__ float gxs[32][3];
    __shared__ float h1s[32][H1PAD];
    __shared__ float h2s[32][H1PAD];
    __shared__ float rsum[256];
    const int tid = threadIdx.x;
    const int c = tid & 63;
    const int rq = tid >> 6;
    const int lg = c >> 4, lm = c & 15;
    const int c2 = rq*16 + lm;
    const float w0c0 = w0[c], w0c1 = w0[64+c], w0c2 = w0[128+c];
    const float b0c = b0[c], sc0 = bnp[c], sh0 = bnp[64+c];
    const float b1c2 = b1[c2], sc1 = bnp[128+c2], sh1 = bnp[192+c2];
    frag_u Bw1[2];
    Bw1[0].u4 = *(const uint4*)&w1b[((0*4 + rq)*64 + c)*4];
    Bw1[1].u4 = *(const uint4*)&w1b[((1*4 + rq)*64 + c)*4];
    f32x4 Ga[4] = {{0,0,0,0},{0,0,0,0},{0,0,0,0},{0,0,0,0}};
    float sumh = 0.f;
    for (int chunk = blockIdx.x; chunk < NROWS/32; chunk += gridDim.x) {
        if (tid < 96) ((float*)gxs)[tid] = gxws[(size_t)chunk*96 + tid];
        __syncthreads();
        #pragma unroll
        for (int i = 0; i < 8; ++i) {
            const int r = rq*8 + i;
            const float t0 = gxs[r][0]*w0c0 + gxs[r][1]*w0c1 + gxs[r][2]*w0c2 + b0c;
            h1s[r][c] = fmaxf(sc0*t0 + sh0, 0.f);
        }
        __syncthreads();
        #pragma unroll
        for (int mt = 0; mt < 2; ++mt) {
            f32x4 acc = {0,0,0,0};
            #pragma unroll
            for (int kt = 0; kt < 2; ++kt) {
                frag_u a;
                #pragma unroll
                for (int r = 0; r < 4; ++r) {
                    const float2 f = *(const float2*)&h1s[mt*16 + lm][kt*32 + lg*8 + 2*r];
                    a.u[r] = pack_bf16pair(f.x, f.y);
                }
                acc = __builtin_amdgcn_mfma_f32_16x16x32_bf16(a.h, Bw1[kt].h, acc, 0, 0, 0);
            }
            #pragma unroll
            for (int r = 0; r < 4; ++r)
                h2s[mt*16 + lg*4 + r][c2] = fmaxf(sc1*(acc[r] + b1c2) + sh1, 0.f);
        }
        __syncthreads();
        #pragma unroll
        for (int i = 0; i < 8; ++i) sumh += h2s[rq*8 + i][c];
        frag_u fr[4];
        #pragma unroll
        for (int ct = 0; ct < 4; ++ct)
            #pragma unroll
            for (int r = 0; r < 4; ++r)
                fr[ct].u[r] = pack_bf16pair(h2s[lg*8 + 2*r][ct*16 + lm],
                                            h2s[lg*8 + 2*r + 1][ct*16 + lm]);
        #pragma unroll
        for (int ct = 0; ct < 4; ++ct)
            Ga[ct] = __builtin_amdgcn_mfma_f32_16x16x32_bf16(fr[rq].h, fr[ct].h, Ga[ct], 0, 0, 0);
        __syncthreads();
    }
    #pragma unroll
    for (int ct = 0; ct < 4; ++ct)
        #pragma unroll
        for (int r = 0; r < 4; ++r)
            atomicAdd(&G2[(rq*16 + lg*4 + r)*64 + ct*16 + lm], Ga[ct][r]);
    rsum[tid] = sumh;
    __syncthreads();
    if (tid < 64) atomicAdd(&Sh2[c], (double)(rsum[c] + rsum[64+c] + rsum[128+c] + rsum[192+c]));
}

__global__ __launch_bounds__(256) void bn_gram_finalize_kernel(
    const double* __restrict__ Sh, const float* __restrict__ G,
    const float* __restrict__ w, const float* __restrict__ bias,
    const float* __restrict__ g, const float* __restrict__ be,
    float* __restrict__ outp)
{
    __shared__ float wls[64][65];
    __shared__ double shl[64];
    __shared__ double rd[256], rqd[256];
    const int tid = threadIdx.x;
    const int c = tid & 63;
    const int rqi = tid >> 6;
    for (int i = tid; i < 4096; i += 256) wls[i >> 6][i & 63] = w[i];
    if (tid < 64) shl[tid] = Sh[tid];
    __syncthreads();
    double dot = 0.0, quad = 0.0;
    for (int j = rqi*16; j < rqi*16 + 16; ++j) {
        const double wjc = (double)wls[j][c];
        dot += wjc * shl[j];
        double inner = 0.0;
        for (int k = 0; k < 64; ++k) inner += (double)G[j*64 + k] * (double)wls[k][c];
        quad += wjc * inner;
    }
    rd[tid] = dot; rqd[tid] = quad;
    __syncthreads();
    if (tid < 64) {
        const double d = rd[c] + rd[64+c] + rd[128+c] + rd[192+c];
        const double q = rqd[c] + rqd[64+c] + rqd[128+c] + rqd[192+c];
        const double N = (double)NROWS;
        const double bc = (double)bias[c];
        const double mean = d / N + bc;
        const double ex2 = (q + 2.0*bc*d) / N + bc*bc;
        const double var = ex2 - mean*mean;
        const float scale = g[c] * rsqrtf((float)var + BN_EPS);
        outp[c] = scale;
        outp[64 + c] = be[c] - (float)mean * scale;
    }
}

__global__ void bn_finalize_kernel(const double* __restrict__ st,
                                   const float* __restrict__ g,
                                   const float* __restrict__ be,
                                   float* __restrict__ outp, float n)
{
    const int c = threadIdx.x;  // 64
    const double m = st[c] / (double)n;
    const double var = st[64 + c] / (double)n - m * m;
    const float scale = g[c] * rsqrtf((float)var + BN_EPS);
    outp[c] = scale;
    outp[64 + c] = be[c] - (float)m * scale;
}

// ============================ final fused conv ============================
// (validated r12 — gxws + tfeat paths; untouched)
__global__ __launch_bounds__(256) void final_conv_kernel(
    const float* __restrict__ gxws,
    const int* __restrict__ idxws, const unsigned short* __restrict__ tfeat,
    const float* __restrict__ w0, const float* __restrict__ b0,
    const float* __restrict__ b1, const float* __restrict__ b2,
    const float* __restrict__ bnp, const unsigned* __restrict__ wfb,
    const unsigned* __restrict__ w1b, const unsigned* __restrict__ w2b,
    const float* __restrict__ bf, float* __restrict__ y)
{
    __shared__ unsigned wtp[8][16][64];
    __shared__ __align__(16) float scratch[2*64*H1PAD];
    __shared__ float gxs[256][3];
    __shared__ int   idxs[8][32];
    float* h1s = scratch;
    float* h2s = scratch + 64*H1PAD;
    unsigned* yaf = (unsigned*)scratch;
    const int tid = threadIdx.x;
    const int c = tid & 63;
    const int rq = tid >> 6;
    const int lg = c >> 4, lm = c & 15;
    const int c2 = rq*16 + lm;
    const int bs0 = blockIdx.x * 8;
    const int b = bs0 >> 10;
    idxs[tid >> 5][tid & 31] = idxws[(size_t)bs0 * NKNN + tid];
    const float w0c0 = w0[c], w0c1 = w0[64+c], w0c2 = w0[128+c];
    const float b0c = b0[c], sc0 = bnp[c], sh0 = bnp[64+c];
    const float b1c2 = b1[c2], sc1 = bnp[128+c2], sh1 = bnp[192+c2];
    const float b2c2 = b2[c2], sc2 = bnp[256+c2], sh2 = bnp[320+c2];
    frag_u Bw1[2], Bw2[2];
    #pragma unroll
    for (int kt = 0; kt < 2; ++kt) {
        Bw1[kt].u4 = *(const uint4*)&w1b[((kt*4 + rq)*64 + c)*4];
        Bw2[kt].u4 = *(const uint4*)&w2b[((kt*4 + rq)*64 + c)*4];
    }
    for (int i = tid; i < 768; i += 256)
        ((float*)gxs)[i] = gxws[(size_t)bs0*96 + i];
    __syncthreads();
    for (int chunk = 0; chunk < 4; ++chunk) {
        #pragma unroll
        for (int i = 0; i < 16; ++i) {
            const int r = rq*16 + i;
            const int gr = chunk*64 + r;
            const float t0 = gxs[gr][0]*w0c0 + gxs[gr][1]*w0c1 + gxs[gr][2]*w0c2 + b0c;
            h1s[r*H1PAD + c] = fmaxf(sc0*t0 + sh0, 0.f);
        }
        __syncthreads();
        #pragma unroll
        for (int mt = 0; mt < 4; ++mt) {
            f32x4 acc = {0,0,0,0};
            #pragma unroll
            for (int kt = 0; kt < 2; ++kt) {
                frag_u a;
                #pragma unroll
                for (int r = 0; r < 4; ++r) {
                    const float2 f = *(const float2*)&h1s[(mt*16 + lm)*H1PAD + kt*32 + lg*8 + 2*r];
                    a.u[r] = pack_bf16pair(f.x, f.y);
                }
                acc = __builtin_amdgcn_mfma_f32_16x16x32_bf16(a.h, Bw1[kt].h, acc, 0, 0, 0);
            }
            #pragma unroll
            for (int r = 0; r < 4; ++r)
                h2s[(mt*16 + lg*4 + r)*H1PAD + c2] = fmaxf(sc1*(acc[r] + b1c2) + sh1, 0.f);
        }
        __syncthreads();
        #pragma unroll
        for (int mt = 0; mt < 4; ++mt) {
            f32x4 acc = {0,0,0,0};
            #pragma unroll
            for (int kt = 0; kt < 2; ++kt) {
                frag_u a;
                #pragma unroll
                for (int r = 0; r < 4; ++r) {
                    const float2 f = *(const float2*)&h2s[(mt*16 + lm)*H1PAD + kt*32 + lg*8 + 2*r];
                    a.u[r] = pack_bf16pair(f.x, f.y);
                }
                acc = __builtin_amdgcn_mfma_f32_16x16x32_bf16(a.h, Bw2[kt].h, acc, 0, 0, 0);
            }
            float wt[4];
            #pragma unroll
            for (int r = 0; r < 4; ++r)
                wt[r] = fmaxf(sc2*(acc[r] + b2c2) + sh2, 0.f);
            const int grow0 = chunk*64 + mt*16 + lg*4;
            const int e = grow0 >> 5, kl = grow0 & 31;
            wtp[e][kl >> 1][c2]       = pack_bf16pair(wt[0], wt[1]);
            wtp[e][(kl >> 1) + 1][c2] = pack_bf16pair(wt[2], wt[3]);
        }
        __syncthreads();
    }
    const int lane = c;
    const int wid = rq;
    frag_u afr[2][4];
    #pragma unroll
    for (int es = 0; es < 2; ++es)
        #pragma unroll
        for (int w4 = 0; w4 < 4; ++w4)
            #pragma unroll
            for (int r = 0; r < 4; ++r)
                afr[es][w4].u[r] = wtp[wid*2 + es][lg*4 + r][w4*16 + lm];
    f32x4 yaccA = {0.f, 0.f, 0.f, 0.f};
    f32x4 yaccB = {0.f, 0.f, 0.f, 0.f};
    const unsigned short* tfb = tfeat + (size_t)b * NPTS * 64;
    for (int dhalf = 0; dhalf < 2; ++dhalf) {
        #pragma unroll
        for (int es = 0; es < 2; ++es) {
            const int e = wid*2 + es;
            #pragma unroll
            for (int dt = 0; dt < 2; ++dt) {
                const int d = dhalf*32 + dt*16 + lm;
                frag_u B;
                #pragma unroll
                for (int r = 0; r < 4; ++r) {
                    const int k0 = lg*8 + 2*r;
                    const unsigned va = tfb[(size_t)idxs[e][k0]   * 64 + d];
                    const unsigned vb = tfb[(size_t)idxs[e][k0+1] * 64 + d];
                    B.u[r] = va | (vb << 16);
                }
                #pragma unroll
                for (int w4 = 0; w4 < 4; ++w4) {
                    f32x4 dnf = {0.f, 0.f, 0.f, 0.f};
                    dnf = __builtin_amdgcn_mfma_f32_16x16x32_bf16(afr[es][w4].h, B.h, dnf, 0, 0, 0);
                    const unsigned p0 = pack_bf16pair(dnf[0], dnf[1]);
                    const unsigned p1 = pack_bf16pair(dnf[2], dnf[3]);
                    const int dloc = dt*16 + lm;
                    const int kp0 = dloc*32 + w4*8 + lg*2;
                    const int sw = kp0 ^ ((lm & 3) << 3) ^ ((e & 7) << 2);
                    *(uint2*)&yaf[e*1024 + sw] = make_uint2(p0, p1);
                }
            }
        }
        __syncthreads();
        for (int kt = 0; kt < 64; kt += 2) {
            frag_u A0, B0, A1, B1;
            const int kpb0 = (kt*16 + lg*4) ^ (((kt >> 1) & 3) << 3) ^ ((lm & 7) << 2);
            const int kpb1 = ((kt+1)*16 + lg*4) ^ ((((kt+1) >> 1) & 3) << 3) ^ ((lm & 7) << 2);
            A0.u4 = *(const uint4*)&yaf[(lm & 7)*1024 + kpb0];
            A1.u4 = *(const uint4*)&yaf[(lm & 7)*1024 + kpb1];
            B0.u4 = *(const uint4*)&wfb[(((size_t)(dhalf*64 + kt)*4 + wid)*64 + lane)*4];
            B1.u4 = *(const uint4*)&wfb[(((size_t)(dhalf*64 + kt + 1)*4 + wid)*64 + lane)*4];
            yaccA = __builtin_amdgcn_mfma_f32_16x16x32_bf16(A0.h, B0.h, yaccA, 0, 0, 0);
            yaccB = __builtin_amdgcn_mfma_f32_16x16x32_bf16(A1.h, B1.h, yaccB, 0, 0, 0);
        }
        __syncthreads();
    }
    if (lg < 2) {
        const float bfo = bf[wid*16 + lm];
        #pragma unroll
        for (int r = 0; r < 4; ++r)
            y[(size_t)(bs0 + lg*4 + r) * 64 + wid*16 + lm] = (yaccA[r] + yaccB[r]) + bfo;
    }
}

__global__ __launch_bounds__(256) void ystats_kernel(const float* __restrict__ y,
                                                     double* __restrict__ st)
{
    const int tid = threadIdx.x;
    const int c = tid & 63;
    double s = 0.0, s2 = 0.0;
    for (int i = blockIdx.x * 256 + tid; i < NBATCH*NSAMP*64; i += gridDim.x * 256) {
        const float v = y[i];
        s += v; s2 += (double)v * (double)v;
    }
    __shared__ double rs[256], rs2[256];
    rs[tid] = s; rs2[tid] = s2;
    __syncthreads();
    if (tid < 64) {
        const double a  = rs[c]  + rs[64+c]  + rs[128+c]  + rs[192+c];
        const double a2 = rs2[c] + rs2[64+c] + rs2[128+c] + rs2[192+c];
        atomicAdd(&st[c], a);
        atomicAdd(&st[64 + c], a2);
    }
}

__global__ void writeout_kernel(const float* __restrict__ y,
                                const float* __restrict__ bnp3,
                                float* __restrict__ outp)
{
    const int i = blockIdx.x * 256 + threadIdx.x;
    if (i >= NBATCH * 64 * NSAMP) return;
    const int s = i & 1023;
    const int o = (i >> 10) & 63;
    const int bb = i >> 16;
    const float v = y[((size_t)(bb << 10) + s) * 64 + o];
    outp[i] = fmaxf(bnp3[o] * v + bnp3[64 + o], 0.f);
}

// ============================ launch ============================
extern "C" void kernel_launch(void* const* d_in, const int* in_sizes, int n_in,
                              void* d_out, int out_size, void* d_ws, size_t ws_size,
                              hipStream_t stream)
{
    (void)in_sizes; (void)n_in; (void)out_size; (void)ws_size;
    const float* xyz  = (const float*)d_in[0];
    const float* feat = (const float*)d_in[1];
    const float* w0   = (const float*)d_in[2];
    const float* b0   = (const float*)d_in[3];
    const float* g0   = (const float*)d_in[4];
    const float* be0  = (const float*)d_in[5];
    const float* w1   = (const float*)d_in[6];
    const float* b1   = (const float*)d_in[7];
    const float* g1   = (const float*)d_in[8];
    const float* be1  = (const float*)d_in[9];
    const float* w2   = (const float*)d_in[10];
    const float* b2   = (const float*)d_in[11];
    const float* g2   = (const float*)d_in[12];
    const float* be2  = (const float*)d_in[13];
    const float* wf   = (const float*)d_in[14];
    const float* bf   = (const float*)d_in[15];
    const float* gf   = (const float*)d_in[16];
    const float* bef  = (const float*)d_in[17];

    float* out = (float*)d_out;
    float* newxyz = out;                       // (B, S, 3)
    float* outmain = out + NBATCH * NSAMP * 3; // (B, 64, S)

    char* ws = (char*)d_ws;
    int*      idxws = (int*)ws;                            // 2 MB
    float*    ybuf  = (float*)(ws + 2097152);              // 4 MB
    double*   stats = (double*)(ws + 6291456);             // 4 KB
    float*    bnp   = (float*)(ws + 6295552);              // 2 KB
    unsigned* wfb   = (unsigned*)(ws + 6297600);           // 512 KB
    unsigned* w1b   = (unsigned*)(ws + 6821888);           // 8 KB
    unsigned* w2b   = (unsigned*)(ws + 6830080);           // 8 KB
    float*    G1    = (float*)(ws + 6838272);              // 16 KB
    float*    G2    = (float*)(ws + 6854656);              // 16 KB
    float*    gxws  = (float*)(ws + 6871040);              // 6 MB (NROWS*12B)
    unsigned short* tfeat = (unsigned short*)(ws + 13164544); // 8 MB

    prep_kernel<<<1188, 256, 0, stream>>>(xyz, newxyz, feat, tfeat,
                                          wf, w1, w2, wfb, w1b, w2b,
                                          stats, G1, G2);
    knn_kernel<<<NBATCH * NSAMP, 256, 0, stream>>>(xyz, newxyz, idxws, gxws);

    gxmoments_kernel<<<1024, 256, 0, stream>>>(gxws, stats);
    bn0_moments_finalize_kernel<<<1, 64, 0, stream>>>(stats, w0, b0, g0, be0, bnp);
    gram1_kernel<<<256, 256, 0, stream>>>(gxws, w0, b0, bnp, G1, stats + 128);
    bn_gram_finalize_kernel<<<1, 256, 0, stream>>>(stats + 128, G1, w1, b1, g1, be1, bnp + 128);
    gram2_kernel<<<256, 256, 0, stream>>>(gxws, w0, b0, b1, w1b, bnp, G2, stats + 192);
    bn_gram_finalize_kernel<<<1, 256, 0, stream>>>(stats + 192, G2, w2, b2, g2, be2, bnp + 256);

    final_conv_kernel<<<NBATCH * NSAMP / 8, 256, 0, stream>>>(
        gxws, idxws, tfeat, w0, b0, b1, b2, bnp, wfb, w1b, w2b, bf, ybuf);

    ystats_kernel<<<256, 256, 0, stream>>>(ybuf, stats + 384);
    bn_finalize_kernel<<<1, 64, 0, stream>>>(stats + 384, gf, bef, bnp + 384, (float)(NBATCH * NSAMP));
    writeout_kernel<<<4096, 256, 0, stream>>>(ybuf, bnp + 384, outmain);
}

// Round 14
// 1219.354 us; speedup vs baseline: 1.1452x; 1.0096x over previous
//
#include <hip/hip_runtime.h>

#define NBATCH 16
#define NPTS   4096
#define NSAMP  1024
#define NKNN   32
#define NROWS  (NBATCH*NSAMP*NKNN)   // 524288
#define BN_EPS 1e-5f
#define H1PAD  66
#define KNN_CAP 512

typedef __attribute__((ext_vector_type(4))) float f32x4;
typedef __attribute__((ext_vector_type(8))) short bf16x8;
union frag_u { unsigned u[4]; bf16x8 h; uint4 u4; };

__device__ __forceinline__ unsigned pack_bf16pair(float a, float b) {
    unsigned ua = __float_as_uint(a); ua += 0x7FFFu + ((ua >> 16) & 1u);
    unsigned ub = __float_as_uint(b); ub += 0x7FFFu + ((ub >> 16) & 1u);
    return (ua >> 16) | (ub & 0xFFFF0000u);
}
__device__ __forceinline__ unsigned short bf16_rne(float a) {
    unsigned ua = __float_as_uint(a); ua += 0x7FFFu + ((ua >> 16) & 1u);
    return (unsigned short)(ua >> 16);
}

// ============================ prep (fps + transpose + wfpack + zero) =======
// (validated r13 — fps body bit-identical since r5)
union PrepLds {
    struct {
        float xs[NPTS]; float ys[NPTS]; float zs[NPTS];
        float4 red[2][4];
        float nxs[NSAMP*3];
    } f;
    unsigned short tt[64][65];
};

__global__ __launch_bounds__(256) void prep_kernel(
    const float* __restrict__ xyz, float* __restrict__ newxyz,
    const float* __restrict__ feat, unsigned short* __restrict__ tfeat,
    const float* __restrict__ wf, const float* __restrict__ w1,
    const float* __restrict__ w2, unsigned* __restrict__ wfb,
    unsigned* __restrict__ w1b, unsigned* __restrict__ w2b,
    double* __restrict__ st, float* __restrict__ g1f, float* __restrict__ g2f)
{
    __shared__ PrepLds L;
    const int blk = blockIdx.x;
    const int tid = threadIdx.x;
    if (blk >= 1172) {               // ---- zero role ----
        const int i = (blk - 1172) * 256 + tid;
        if (i < 512) st[i] = 0.0;
        if (i < 4096) { g1f[i] = 0.f; g2f[i] = 0.f; }
        return;
    }
    if (blk >= 1040) {               // ---- wfpack role (4 units/block) ----
        const int unit = (blk - 1040) * 4 + (tid >> 6);
        const int l = tid & 63;
        int u = unit;
        const float* src; unsigned* dst;
        if (u < 512)      { src = wf; dst = wfb; }
        else if (u < 520) { src = w1; dst = w1b; u -= 512; }
        else              { src = w2; dst = w2b; u -= 520; }
        const int kt = u >> 2, ot = u & 3;
        const int o = ot*16 + (l & 15);
        const int kb = kt*32 + (l >> 4)*8;
        unsigned outp[4];
        #pragma unroll
        for (int r = 0; r < 4; ++r) {
            const float a = src[(size_t)(kb + 2*r) * 64 + o];
            const float b = src[(size_t)(kb + 2*r + 1) * 64 + o];
            outp[r] = pack_bf16pair(a, b);
        }
        *(uint4*)&dst[((size_t)u * 64 + l) * 4] = *(const uint4*)outp;
        return;
    }
    if (blk >= 16) {                 // ---- feat transpose role ----
        const int t = blk - 16;       // 0..1023
        const int b = t >> 6, nt = t & 63;
        #pragma unroll
        for (int i = 0; i < 16; ++i) {
            const int e = i*256 + tid;
            const int d = e >> 6, n = e & 63;
            L.tt[n][d] = bf16_rne(feat[((size_t)(b*64 + d))*NPTS + nt*64 + n]);
        }
        __syncthreads();
        #pragma unroll
        for (int i = 0; i < 16; ++i) {
            const int e = i*256 + tid;
            const int n = e >> 6, d = e & 63;
            tfeat[((size_t)(b*NPTS) + nt*64 + n)*64 + d] = L.tt[n][d];
        }
        return;
    }
    // ---- fps role ----
    const int b = blk;
    const int wv = tid >> 6;
    const float* xb = xyz + (size_t)b * NPTS * 3;
    float px[16], py[16], pz[16], dmin[16];
    {
        float arr[48];
        const float4* s4 = (const float4*)(xb + (size_t)tid * 48);
        #pragma unroll
        for (int i = 0; i < 12; ++i) *(float4*)&arr[i*4] = s4[i];
        #pragma unroll
        for (int j = 0; j < 16; ++j) {
            px[j] = arr[3*j]; py[j] = arr[3*j+1]; pz[j] = arr[3*j+2];
            const int p = tid * 16 + j;
            L.f.xs[p] = px[j]; L.f.ys[p] = py[j]; L.f.zs[p] = pz[j];
            dmin[j] = 1e10f;
        }
    }
    if (tid == 0) { L.f.nxs[0] = xb[0]; L.f.nxs[1] = xb[1]; L.f.nxs[2] = xb[2]; }
    __syncthreads();
    float lx = L.f.xs[0], ly = L.f.ys[0], lz = L.f.zs[0];
    for (int t = 1; t < NSAMP; ++t) {
        float bv = -1.0f;
        #pragma unroll
        for (int j = 0; j < 16; ++j) {
            const float dx = __fsub_rn(px[j], lx);
            const float dy = __fsub_rn(py[j], ly);
            const float dz = __fsub_rn(pz[j], lz);
            const float d = __fadd_rn(__fadd_rn(__fmul_rn(dx,dx), __fmul_rn(dy,dy)), __fmul_rn(dz,dz));
            const float nd = fminf(dmin[j], d);
            dmin[j] = nd;
            bv = fmaxf(bv, nd);
        }
        int lj = 0;
        #pragma unroll
        for (int j = 15; j >= 0; --j) if (dmin[j] == bv) lj = j;
        const int bi_lane = tid * 16 + lj;
        float mv = bv;
        {
            int s_;
            s_ = __builtin_amdgcn_mov_dpp(__float_as_int(mv), 0x111, 0xf, 0xf, true);
            mv = fmaxf(mv, __int_as_float(s_));
            s_ = __builtin_amdgcn_mov_dpp(__float_as_int(mv), 0x112, 0xf, 0xf, true);
            mv = fmaxf(mv, __int_as_float(s_));
            s_ = __builtin_amdgcn_mov_dpp(__float_as_int(mv), 0x114, 0xf, 0xf, true);
            mv = fmaxf(mv, __int_as_float(s_));
            s_ = __builtin_amdgcn_mov_dpp(__float_as_int(mv), 0x118, 0xf, 0xf, true);
            mv = fmaxf(mv, __int_as_float(s_));
            s_ = __builtin_amdgcn_mov_dpp(__float_as_int(mv), 0x142, 0xf, 0xf, true);
            mv = fmaxf(mv, __int_as_float(s_));
            s_ = __builtin_amdgcn_mov_dpp(__float_as_int(mv), 0x143, 0xf, 0xf, true);
            mv = fmaxf(mv, __int_as_float(s_));
        }
        mv = __int_as_float(__builtin_amdgcn_readlane(__float_as_int(mv), 63));
        const unsigned long long mask = __ballot(bv == mv);
        const int winner = __ffsll(mask) - 1;
        const int bi_w = __builtin_amdgcn_readlane(bi_lane, winner);
        const float wx = L.f.xs[bi_w], wy = L.f.ys[bi_w], wz = L.f.zs[bi_w];
        const int par = t & 1;
        if ((tid & 63) == 0) L.f.red[par][wv] = make_float4(mv, wx, wy, wz);
        __syncthreads();
        float4 w0 = L.f.red[par][0];
        const float4 w1v = L.f.red[par][1];
        const float4 w2v = L.f.red[par][2];
        const float4 w3v = L.f.red[par][3];
        if (w1v.x > w0.x) w0 = w1v;
        if (w2v.x > w0.x) w0 = w2v;
        if (w3v.x > w0.x) w0 = w3v;
        lx = w0.y; ly = w0.z; lz = w0.w;
        if (tid == 0) { L.f.nxs[t*3] = lx; L.f.nxs[t*3+1] = ly; L.f.nxs[t*3+2] = lz; }
    }
    __syncthreads();
    {
        float4* d4 = (float4*)(newxyz + (size_t)b * NSAMP * 3);
        const float4* s4 = (const float4*)L.f.nxs;
        #pragma unroll
        for (int i = tid; i < NSAMP*3/4; i += 256) d4[i] = s4[i];
    }
}

// ============================ kNN v4 ============================
// (validated r13 — selection + gx emission untouched)
__device__ __forceinline__ void bin_select(int* hist, int* ctrl, int* wsum,
                                           int tid, int shift)
{
    const int lane = tid & 63, wv = tid >> 6;
    const int cnt = hist[tid];
    const int r = ctrl[1];
    int incl = cnt;
    #pragma unroll
    for (int d = 1; d < 64; d <<= 1) {
        const int v = __shfl_up(incl, d);
        if (lane >= d) incl += v;
    }
    if (lane == 63) wsum[wv] = incl;
    __syncthreads();
    int base = 0;
    if (wv > 0) base += wsum[0];
    if (wv > 1) base += wsum[1];
    if (wv > 2) base += wsum[2];
    incl += base;
    const int excl = incl - cnt;
    if (excl < r && r <= incl) {
        ctrl[0] |= tid << shift;
        ctrl[1] = r - excl;
        ctrl[2] = cnt;
    }
}

__global__ __launch_bounds__(256) void knn_kernel(const float* __restrict__ xyz,
                                                  const float* __restrict__ newxyz,
                                                  int* __restrict__ idx_out,
                                                  float* __restrict__ gxws)
{
    const int bs = blockIdx.x;
    const int b = bs >> 10;
    const int tid = threadIdx.x;
    const int lane = tid & 63;
    __shared__ unsigned keys[NPTS];
    __shared__ int hist[256];
    __shared__ float qsh[3];
    __shared__ int ctrl[8];
    __shared__ int wsum[4];
    __shared__ int cl[KNN_CAP];
    __shared__ int lt[32];
    __shared__ int ties[128];
    __shared__ int outl[NKNN];
    if (tid < 3) qsh[tid] = newxyz[bs*3 + tid];
    if (tid == 0) { ctrl[0] = 0; ctrl[1] = NKNN; }
    hist[tid] = 0;
    __syncthreads();
    const float q0 = qsh[0], q1 = qsh[1], q2 = qsh[2];
    const float qq = __fadd_rn(__fadd_rn(__fmul_rn(q0,q0), __fmul_rn(q1,q1)), __fmul_rn(q2,q2));
    const float* xb = xyz + (size_t)b * NPTS * 3;
    for (int n = tid; n < NPTS; n += 256) {
        const float x0 = xb[n*3+0], x1 = xb[n*3+1], x2 = xb[n*3+2];
        const float xx = __fadd_rn(__fadd_rn(__fmul_rn(x0,x0), __fmul_rn(x1,x1)), __fmul_rn(x2,x2));
        float dt = __fmul_rn(q0, x0);
        dt = __fmaf_rn(q1, x1, dt);
        dt = __fmaf_rn(q2, x2, dt);
        const float dd = __fadd_rn(__fsub_rn(qq, __fmul_rn(2.0f, dt)), xx);
        unsigned ub = __float_as_uint(dd);
        ub = (ub & 0x80000000u) ? ~ub : (ub | 0x80000000u);
        keys[n] = ub;
        const int bin = (int)(ub >> 24);
        unsigned long long act = __ballot(true);
        while (act) {
            const int leader = __ffsll(act) - 1;
            const int lbin = __builtin_amdgcn_readlane(bin, leader);
            const unsigned long long same = __ballot(bin == lbin);
            if (lane == leader) atomicAdd(&hist[lbin], (int)__popcll(same));
            act &= ~same;
        }
    }
    __syncthreads();
    bin_select(hist, ctrl, wsum, tid, 24);
    __syncthreads();
    const unsigned pf3 = (unsigned)ctrl[0];
    const int bin3 = (int)(pf3 >> 24);
    const int m = ctrl[2];
    const bool compact = (m <= KNN_CAP);
    if (tid == 0) { ctrl[3] = 0; ctrl[4] = 0; ctrl[5] = 0; ctrl[6] = 0; }
    __syncthreads();
    if (compact) {
        for (int n = tid; n < NPTS; n += 256) {
            const int tb = (int)(keys[n] >> 24);
            if (tb == bin3)      { const int pos = atomicAdd(&ctrl[3], 1); cl[pos] = n; }
            else if (tb < bin3)  { const int pos = atomicAdd(&ctrl[4], 1); lt[pos] = n; }
        }
    }
    __syncthreads();
    for (int p = 2; p >= 0; --p) {
        hist[tid] = 0;
        __syncthreads();
        const unsigned pre = (unsigned)ctrl[0];
        const int shift = p * 8;
        const unsigned himask = 0xFFFFFFFFu << ((p + 1) * 8);
        if (compact) {
            const int eqn = ctrl[3];
            for (int i = tid; i < eqn; i += 256) {
                const unsigned k = keys[cl[i]];
                if ((k & himask) == pre) atomicAdd(&hist[(k >> shift) & 255], 1);
            }
        } else {
            for (int n = tid; n < NPTS; n += 256) {
                const unsigned k = keys[n];
                if ((k & himask) == pre) atomicAdd(&hist[(k >> shift) & 255], 1);
            }
        }
        __syncthreads();
        bin_select(hist, ctrl, wsum, tid, shift);
        __syncthreads();
    }
    const unsigned T = (unsigned)ctrl[0];
    if (compact) {
        const int ltn = ctrl[4];
        if (tid == 0) ctrl[5] = ltn;
        __syncthreads();
        if (tid < ltn) outl[tid] = lt[tid];
        const int eqn = ctrl[3];
        for (int i = tid; i < eqn; i += 256) {
            const int n = cl[i];
            const unsigned k = keys[n];
            if (k < T) {
                const int pos = atomicAdd(&ctrl[5], 1);
                if (pos < NKNN) outl[pos] = n;
            } else if (k == T) {
                const int pos = atomicAdd(&ctrl[6], 1);
                if (pos < 128) ties[pos] = n;
            }
        }
    } else {
        for (int n = tid; n < NPTS; n += 256) {
            const unsigned k = keys[n];
            if (k < T) {
                const int pos = atomicAdd(&ctrl[5], 1);
                if (pos < NKNN) outl[pos] = n;
            } else if (k == T) {
                const int pos = atomicAdd(&ctrl[6], 1);
                if (pos < 128) ties[pos] = n;
            }
        }
    }
    __syncthreads();
    if (tid == 0) {
        const int nless = ctrl[5] < NKNN ? ctrl[5] : NKNN;
        const int need = NKNN - nless;
        const int ntie = ctrl[6] < 128 ? ctrl[6] : 128;
        int last = -1;
        for (int j = 0; j < need; ++j) {
            int best = 0x7fffffff;
            for (int i = 0; i < ntie; ++i) {
                const int v = ties[i];
                if (v > last && v < best) best = v;
            }
            outl[nless + j] = (best == 0x7fffffff) ? 0 : best;
            last = best;
        }
    }
    __syncthreads();
    if (tid < NKNN) idx_out[(size_t)bs * NKNN + tid] = outl[tid];
    if (tid < 96) {
        const int k = tid / 3, cc = tid % 3;
        gxws[((size_t)bs * NKNN + k) * 3 + cc] = xb[outl[k]*3 + cc] - qsh[cc];
    }
}

// ============================ moments (linear read) ============================
__global__ __launch_bounds__(256) void gxmoments_kernel(
    const float* __restrict__ gxws, double* __restrict__ stats)
{
    const int tid = threadIdx.x;
    float m[9];
    #pragma unroll
    for (int i = 0; i < 9; ++i) m[i] = 0.f;
    for (int row = blockIdx.x * 256 + tid; row < NROWS; row += gridDim.x * 256) {
        const float dx = gxws[(size_t)row*3 + 0];
        const float dy = gxws[(size_t)row*3 + 1];
        const float dz = gxws[(size_t)row*3 + 2];
        m[0] += dx; m[1] += dy; m[2] += dz;
        m[3] += dx*dx; m[4] += dx*dy; m[5] += dx*dz;
        m[6] += dy*dy; m[7] += dy*dz; m[8] += dz*dz;
    }
    double d[9];
    #pragma unroll
    for (int i = 0; i < 9; ++i) {
        d[i] = (double)m[i];
        #pragma unroll
        for (int s = 1; s < 64; s <<= 1) d[i] += __shfl_xor(d[i], s);
    }
    __shared__ double part[4][9];
    if ((tid & 63) == 0) {
        #pragma unroll
        for (int i = 0; i < 9; ++i) part[tid >> 6][i] = d[i];
    }
    __syncthreads();
    if (tid < 9) atomicAdd(&stats[tid], part[0][tid] + part[1][tid] + part[2][tid] + part[3][tid]);
}

__global__ void bn0_moments_finalize_kernel(const double* __restrict__ st,
    const float* __restrict__ w0, const float* __restrict__ b0,
    const float* __restrict__ g0, const float* __restrict__ be0,
    float* __restrict__ outp)
{
    const int c = threadIdx.x;  // 64
    const double N = (double)NROWS;
    const double w0c = w0[c], w1c = w0[64 + c], w2c = w0[128 + c];
    const double b = b0[c];
    const double dotS = st[0]*w0c + st[1]*w1c + st[2]*w2c;
    const double qf = w0c*w0c*st[3] + w1c*w1c*st[6] + w2c*w2c*st[8]
                    + 2.0*(w0c*w1c*st[4] + w0c*w2c*st[5] + w1c*w2c*st[7]);
    const double mean = dotS / N + b;
    const double ex2 = (qf + 2.0*b*dotS) / N + b*b;
    const double var = ex2 - mean*mean;
    const float scale = g0[c] * rsqrtf((float)var + BN_EPS);
    outp[c] = scale;
    outp[64 + c] = be0[c] - (float)mean * scale;
}

// ============================ Gram stats (grid 1024, 4 blocks/CU) ==========
__global__ __launch_bounds__(256) void gram1_kernel(
    const float* __restrict__ gxws,
    const float* __restrict__ w0, const float* __restrict__ b0,
    const float* __restrict__ bnp, float* __restrict__ G1,
    double* __restrict__ Sh1)
{
    __shared__ float gxs[32][3];
    __shared__ float h1s[32][H1PAD];
    __shared__ float rsum[256];
    const int tid = threadIdx.x;
    const int c = tid & 63;
    const int rq = tid >> 6;
    const int lg = c >> 4, lm = c & 15;
    const float w0c0 = w0[c], w0c1 = w0[64+c], w0c2 = w0[128+c];
    const float b0c = b0[c], sc0 = bnp[c], sh0 = bnp[64+c];
    f32x4 Ga[4] = {{0,0,0,0},{0,0,0,0},{0,0,0,0},{0,0,0,0}};
    float sumh = 0.f;
    for (int chunk = blockIdx.x; chunk < NROWS/32; chunk += gridDim.x) {
        if (tid < 96) ((float*)gxs)[tid] = gxws[(size_t)chunk*96 + tid];
        __syncthreads();
        #pragma unroll
        for (int i = 0; i < 8; ++i) {
            const int r = rq*8 + i;
            const float t0 = gxs[r][0]*w0c0 + gxs[r][1]*w0c1 + gxs[r][2]*w0c2 + b0c;
            const float h = fmaxf(sc0*t0 + sh0, 0.f);
            h1s[r][c] = h;
            sumh += h;
        }
        __syncthreads();
        frag_u fr[4];
        #pragma unroll
        for (int ct = 0; ct < 4; ++ct)
            #pragma unroll
            for (int r = 0; r < 4; ++r)
                fr[ct].u[r] = pack_bf16pair(h1s[lg*8 + 2*r][ct*16 + lm],
                                            h1s[lg*8 + 2*r + 1][ct*16 + lm]);
        #pragma unroll
        for (int ct = 0; ct < 4; ++ct)
            Ga[ct] = __builtin_amdgcn_mfma_f32_16x16x32_bf16(fr[rq].h, fr[ct].h, Ga[ct], 0, 0, 0);
        __syncthreads();
    }
    #pragma unroll
    for (int ct = 0; ct < 4; ++ct)
        #pragma unroll
        for (int r = 0; r < 4; ++r)
            atomicAdd(&G1[(rq*16 + lg*4 + r)*64 + ct*16 + lm], Ga[ct][r]);
    rsum[tid] = sumh;
    __syncthreads();
    if (tid < 64) atomicAdd(&Sh1[c], (double)(rsum[c] + rsum[64+c] + rsum[128+c] + rsum[192+c]));
}

__global__ __launch_bounds__(256) void gram2_kernel(
    const float* __restrict__ gxws,
    const float* __restrict__ w0, const float* __restrict__ b0,
    const float* __restrict__ b1, const unsigned* __restrict__ w1b,
    const float* __restrict__ bnp, float* __restrict__ G2,
    double* __restrict__ Sh2)
{
    __shared__ float gxs[32][3];
    __shared__ float h1s[32][H1PAD];
    __shared__ float h2s[32][H1PAD];
    __shared__ float rsum[256];
    const int tid = threadIdx.x;
    const int c = tid & 63;
    const int rq = tid >> 6;
    const int lg = c >> 4, lm = c & 15;
    const int c2 = rq*16 + lm;
    const float w0c0 = w0[c], w0c1 = w0[64+c], w0c2 = w0[128+c];
    const float b0c = b0[c], sc0 = bnp[c], sh0 = bnp[64+c];
    const float b1c2 = b1[c2], sc1 = bnp[128+c2], sh1 = bnp[192+c2];
    frag_u Bw1[2];
    Bw1[0].u4 = *(const uint4*)&w1b[((0*4 + rq)*64 + c)*4];
    Bw1[1].u4 = *(const uint4*)&w1b[((1*4 + rq)*64 + c)*4];
    f32x4 Ga[4] = {{0,0,0,0},{0,0,0,0},{0,0,0,0},{0,0,0,0}};
    float sumh = 0.f;
    for (int chunk = blockIdx.x; chunk < NROWS/32; chunk += gridDim.x) {
        if (tid < 96) ((float*)gxs)[tid] = gxws[(size_t)chunk*96 + tid];
        __syncthreads();
        #pragma unroll
        for (int i = 0; i < 8; ++i) {
            const int r = rq*8 + i;
            const float t0 = gxs[r][0]*w0c0 + gxs[r][1]*w0c1 + gxs[r][2]*w0c2 + b0c;
            h1s[r][c] = fmaxf(sc0*t0 + sh0, 0.f);
        }
        __syncthreads();
        #pragma unroll
        for (int mt = 0; mt < 2; ++mt) {
            f32x4 acc = {0,0,0,0};
            #pragma unroll
            for (int kt = 0; kt < 2; ++kt) {
                frag_u a;
                #pragma unroll
                for (int r = 0; r < 4; ++r) {
                    const float2 f = *(const float2*)&h1s[mt*16 + lm][kt*32 + lg*8 + 2*r];
                    a.u[r] = pack_bf16pair(f.x, f.y);
                }
                acc = __builtin_amdgcn_mfma_f32_16x16x32_bf16(a.h, Bw1[kt].h, acc, 0, 0, 0);
            }
            #pragma unroll
            for (int r = 0; r < 4; ++r)
                h2s[mt*16 + lg*4 + r][c2] = fmaxf(sc1*(acc[r] + b1c2) + sh1, 0.f);
        }
        __syncthreads();
        #pragma unroll
        for (int i = 0; i < 8; ++i) sumh += h2s[rq*8 + i][c];
        frag_u fr[4];
        #pragma unroll
        for (int ct = 0; ct < 4; ++ct)
            #pragma unroll
            for (int r = 0; r < 4; ++r)
                fr[ct].u[r] = pack_bf16pair(h2s[lg*8 + 2*r][ct*16 + lm],
                                            h2s[lg*8 + 2*r + 1][ct*16 + lm]);
        #pragma unroll
        for (int ct = 0; ct < 4; ++ct)
            Ga[ct] = __builtin_amdgcn_mfma_f32_16x16x32_bf16(fr[rq].h, fr[ct].h, Ga[ct], 0, 0, 0);
        __syncthreads();
    }
    #pragma unroll
    for (int ct = 0; ct < 4; ++ct)
        #pragma unroll
        for (int r = 0; r < 4; ++r)
            atomicAdd(&G2[(rq*16 + lg*4 + r)*64 + ct*16 + lm], Ga[ct][r]);
    rsum[tid] = sumh;
    __syncthreads();
    if (tid < 64) atomicAdd(&Sh2[c], (double)(rsum[c] + rsum[64+c] + rsum[128+c] + rsum[192+c]));
}

__global__ __launch_bounds__(256) void bn_gram_finalize_kernel(
    const double* __restrict__ Sh, const float* __restrict__ G,
    const float* __restrict__ w, const float* __restrict__ bias,
    const float* __restrict__ g, const float* __restrict__ be,
    float* __restrict__ outp)
{
    __shared__ float wls[64][65];
    __shared__ double shl[64];
    __shared__ double rd[256], rqd[256];
    const int tid = threadIdx.x;
    const int c = tid & 63;
    const int rqi = tid >> 6;
    for (int i = tid; i < 4096; i += 256) wls[i >> 6][i & 63] = w[i];
    if (tid < 64) shl[tid] = Sh[tid];
    __syncthreads();
    double dot = 0.0, quad = 0.0;
    for (int j = rqi*16; j < rqi*16 + 16; ++j) {
        const double wjc = (double)wls[j][c];
        dot += wjc * shl[j];
        double inner = 0.0;
        for (int k = 0; k < 64; ++k) inner += (double)G[j*64 + k] * (double)wls[k][c];
        quad += wjc * inner;
    }
    rd[tid] = dot; rqd[tid] = quad;
    __syncthreads();
    if (tid < 64) {
        const double d = rd[c] + rd[64+c] + rd[128+c] + rd[192+c];
        const double q = rqd[c] + rqd[64+c] + rqd[128+c] + rqd[192+c];
        const double N = (double)NROWS;
        const double bc = (double)bias[c];
        const double mean = d / N + bc;
        const double ex2 = (q + 2.0*bc*d) / N + bc*bc;
        const double var = ex2 - mean*mean;
        const float scale = g[c] * rsqrtf((float)var + BN_EPS);
        outp[c] = scale;
        outp[64 + c] = be[c] - (float)mean * scale;
    }
}

__global__ void bn_finalize_kernel(const double* __restrict__ st,
                                   const float* __restrict__ g,
                                   const float* __restrict__ be,
                                   float* __restrict__ outp, float n)
{
    const int c = threadIdx.x;  // 64
    const double m = st[c] / (double)n;
    const double var = st[64 + c] / (double)n - m * m;
    const float scale = g[c] * rsqrtf((float)var + BN_EPS);
    outp[c] = scale;
    outp[64 + c] = be[c] - (float)m * scale;
}

// ============================ final fused conv (+ ystats fused) ============
__global__ __launch_bounds__(256) void final_conv_kernel(
    const float* __restrict__ gxws,
    const int* __restrict__ idxws, const unsigned short* __restrict__ tfeat,
    const float* __restrict__ w0, const float* __restrict__ b0,
    const float* __restrict__ b1, const float* __restrict__ b2,
    const float* __restrict__ bnp, const unsigned* __restrict__ wfb,
    const unsigned* __restrict__ w1b, const unsigned* __restrict__ w2b,
    const float* __restrict__ bf, float* __restrict__ y,
    double* __restrict__ yst)
{
    __shared__ unsigned wtp[8][16][64];
    __shared__ __align__(16) float scratch[2*64*H1PAD];
    __shared__ float gxs[256][3];
    __shared__ int   idxs[8][32];
    float* h1s = scratch;
    float* h2s = scratch + 64*H1PAD;
    unsigned* yaf = (unsigned*)scratch;
    const int tid = threadIdx.x;
    const int c = tid & 63;
    const int rq = tid >> 6;
    const int lg = c >> 4, lm = c & 15;
    const int c2 = rq*16 + lm;
    const int bs0 = blockIdx.x * 8;
    const int b = bs0 >> 10;
    idxs[tid >> 5][tid & 31] = idxws[(size_t)bs0 * NKNN + tid];
    const float w0c0 = w0[c], w0c1 = w0[64+c], w0c2 = w0[128+c];
    const float b0c = b0[c], sc0 = bnp[c], sh0 = bnp[64+c];
    const float b1c2 = b1[c2], sc1 = bnp[128+c2], sh1 = bnp[192+c2];
    const float b2c2 = b2[c2], sc2 = bnp[256+c2], sh2 = bnp[320+c2];
    frag_u Bw1[2], Bw2[2];
    #pragma unroll
    for (int kt = 0; kt < 2; ++kt) {
        Bw1[kt].u4 = *(const uint4*)&w1b[((kt*4 + rq)*64 + c)*4];
        Bw2[kt].u4 = *(const uint4*)&w2b[((kt*4 + rq)*64 + c)*4];
    }
    for (int i = tid; i < 768; i += 256)
        ((float*)gxs)[i] = gxws[(size_t)bs0*96 + i];
    __syncthreads();
    for (int chunk = 0; chunk < 4; ++chunk) {
        #pragma unroll
        for (int i = 0; i < 16; ++i) {
            const int r = rq*16 + i;
            const int gr = chunk*64 + r;
            const float t0 = gxs[gr][0]*w0c0 + gxs[gr][1]*w0c1 + gxs[gr][2]*w0c2 + b0c;
            h1s[r*H1PAD + c] = fmaxf(sc0*t0 + sh0, 0.f);
        }
        __syncthreads();
        #pragma unroll
        for (int mt = 0; mt < 4; ++mt) {
            f32x4 acc = {0,0,0,0};
            #pragma unroll
            for (int kt = 0; kt < 2; ++kt) {
                frag_u a;
                #pragma unroll
                for (int r = 0; r < 4; ++r) {
                    const float2 f = *(const float2*)&h1s[(mt*16 + lm)*H1PAD + kt*32 + lg*8 + 2*r];
                    a.u[r] = pack_bf16pair(f.x, f.y);
                }
                acc = __builtin_amdgcn_mfma_f32_16x16x32_bf16(a.h, Bw1[kt].h, acc, 0, 0, 0);
            }
            #pragma unroll
            for (int r = 0; r < 4; ++r)
                h2s[(mt*16 + lg*4 + r)*H1PAD + c2] = fmaxf(sc1*(acc[r] + b1c2) + sh1, 0.f);
        }
        __syncthreads();
        #pragma unroll
        for (int mt = 0; mt < 4; ++mt) {
            f32x4 acc = {0,0,0,0};
            #pragma unroll
            for (int kt = 0; kt < 2; ++kt) {
                frag_u a;
                #pragma unroll
                for (int r = 0; r < 4; ++r) {
                    const float2 f = *(const float2*)&h2s[(mt*16 + lm)*H1PAD + kt*32 + lg*8 + 2*r];
                    a.u[r] = pack_bf16pair(f.x, f.y);
                }
                acc = __builtin_amdgcn_mfma_f32_16x16x32_bf16(a.h, Bw2[kt].h, acc, 0, 0, 0);
            }
            float wt[4];
            #pragma unroll
            for (int r = 0; r < 4; ++r)
                wt[r] = fmaxf(sc2*(acc[r] + b2c2) + sh2, 0.f);
            const int grow0 = chunk*64 + mt*16 + lg*4;
            const int e = grow0 >> 5, kl = grow0 & 31;
            wtp[e][kl >> 1][c2]       = pack_bf16pair(wt[0], wt[1]);
            wtp[e][(kl >> 1) + 1][c2] = pack_bf16pair(wt[2], wt[3]);
        }
        __syncthreads();
    }
    const int lane = c;
    const int wid = rq;
    frag_u afr[2][4];
    #pragma unroll
    for (int es = 0; es < 2; ++es)
        #pragma unroll
        for (int w4 = 0; w4 < 4; ++w4)
            #pragma unroll
            for (int r = 0; r < 4; ++r)
                afr[es][w4].u[r] = wtp[wid*2 + es][lg*4 + r][w4*16 + lm];
    f32x4 yaccA = {0.f, 0.f, 0.f, 0.f};
    f32x4 yaccB = {0.f, 0.f, 0.f, 0.f};
    const unsigned short* tfb = tfeat + (size_t)b * NPTS * 64;
    for (int dhalf = 0; dhalf < 2; ++dhalf) {
        #pragma unroll
        for (int es = 0; es < 2; ++es) {
            const int e = wid*2 + es;
            #pragma unroll
            for (int dt = 0; dt < 2; ++dt) {
                const int d = dhalf*32 + dt*16 + lm;
                frag_u B;
                #pragma unroll
                for (int r = 0; r < 4; ++r) {
                    const int k0 = lg*8 + 2*r;
                    const unsigned va = tfb[(size_t)idxs[e][k0]   * 64 + d];
                    const unsigned vb = tfb[(size_t)idxs[e][k0+1] * 64 + d];
                    B.u[r] = va | (vb << 16);
                }
                #pragma unroll
                for (int w4 = 0; w4 < 4; ++w4) {
                    f32x4 dnf = {0.f, 0.f, 0.f, 0.f};
                    dnf = __builtin_amdgcn_mfma_f32_16x16x32_bf16(afr[es][w4].h, B.h, dnf, 0, 0, 0);
                    const unsigned p0 = pack_bf16pair(dnf[0], dnf[1]);
                    const unsigned p1 = pack_bf16pair(dnf[2], dnf[3]);
                    const int dloc = dt*16 + lm;
                    const int kp0 = dloc*32 + w4*8 + lg*2;
                    const int sw = kp0 ^ ((lm & 3) << 3) ^ ((e & 7) << 2);
                    *(uint2*)&yaf[e*1024 + sw] = make_uint2(p0, p1);
                }
            }
        }
        __syncthreads();
        for (int kt = 0; kt < 64; kt += 2) {
            frag_u A0, B0, A1, B1;
            const int kpb0 = (kt*16 + lg*4) ^ (((kt >> 1) & 3) << 3) ^ ((lm & 7) << 2);
            const int kpb1 = ((kt+1)*16 + lg*4) ^ ((((kt+1) >> 1) & 3) << 3) ^ ((lm & 7) << 2);
            A0.u4 = *(const uint4*)&yaf[(lm & 7)*1024 + kpb0];
            A1.u4 = *(const uint4*)&yaf[(lm & 7)*1024 + kpb1];
            B0.u4 = *(const uint4*)&wfb[(((size_t)(dhalf*64 + kt)*4 + wid)*64 + lane)*4];
            B1.u4 = *(const uint4*)&wfb[(((size_t)(dhalf*64 + kt + 1)*4 + wid)*64 + lane)*4];
            yaccA = __builtin_amdgcn_mfma_f32_16x16x32_bf16(A0.h, B0.h, yaccA, 0, 0, 0);
            yaccB = __builtin_amdgcn_mfma_f32_16x16x32_bf16(A1.h, B1.h, yaccB, 0, 0, 0);
        }
        __syncthreads();
    }
    if (lg < 2) {
        const float bfo = bf[wid*16 + lm];
        double s = 0.0, s2 = 0.0;
        #pragma unroll
        for (int r = 0; r < 4; ++r) {
            const float v = (yaccA[r] + yaccB[r]) + bfo;
            y[(size_t)(bs0 + lg*4 + r) * 64 + wid*16 + lm] = v;
            s += (double)v; s2 += (double)v * (double)v;
        }
        atomicAdd(&yst[wid*16 + lm], s);
        atomicAdd(&yst[64 + wid*16 + lm], s2);
    }
}

__global__ void writeout_kernel(const float* __restrict__ y,
                                const float* __restrict__ bnp3,
                                float* __restrict__ outp)
{
    const int i = blockIdx.x * 256 + threadIdx.x;
    if (i >= NBATCH * 64 * NSAMP) return;
    const int s = i & 1023;
    const int o = (i >> 10) & 63;
    const int bb = i >> 16;
    const float v = y[((size_t)(bb << 10) + s) * 64 + o];
    outp[i] = fmaxf(bnp3[o] * v + bnp3[64 + o], 0.f);
}

// ============================ launch ============================
extern "C" void kernel_launch(void* const* d_in, const int* in_sizes, int n_in,
                              void* d_out, int out_size, void* d_ws, size_t ws_size,
                              hipStream_t stream)
{
    (void)in_sizes; (void)n_in; (void)out_size; (void)ws_size;
    const float* xyz  = (const float*)d_in[0];
    const float* feat = (const float*)d_in[1];
    const float* w0   = (const float*)d_in[2];
    const float* b0   = (const float*)d_in[3];
    const float* g0   = (const float*)d_in[4];
    const float* be0  = (const float*)d_in[5];
    const float* w1   = (const float*)d_in[6];
    const float* b1   = (const float*)d_in[7];
    const float* g1   = (const float*)d_in[8];
    const float* be1  = (const float*)d_in[9];
    const float* w2   = (const float*)d_in[10];
    const float* b2   = (const float*)d_in[11];
    const float* g2   = (const float*)d_in[12];
    const float* be2  = (const float*)d_in[13];
    const float* wf   = (const float*)d_in[14];
    const float* bf   = (const float*)d_in[15];
    const float* gf   = (const float*)d_in[16];
    const float* bef  = (const float*)d_in[17];

    float* out = (float*)d_out;
    float* newxyz = out;                       // (B, S, 3)
    float* outmain = out + NBATCH * NSAMP * 3; // (B, 64, S)

    char* ws = (char*)d_ws;
    int*      idxws = (int*)ws;                            // 2 MB
    float*    ybuf  = (float*)(ws + 2097152);              // 4 MB
    double*   stats = (double*)(ws + 6291456);             // 4 KB
    float*    bnp   = (float*)(ws + 6295552);              // 2 KB
    unsigned* wfb   = (unsigned*)(ws + 6297600);           // 512 KB
    unsigned* w1b   = (unsigned*)(ws + 6821888);           // 8 KB
    unsigned* w2b   = (unsigned*)(ws + 6830080);           // 8 KB
    float*    G1    = (float*)(ws + 6838272);              // 16 KB
    float*    G2    = (float*)(ws + 6854656);              // 16 KB
    float*    gxws  = (float*)(ws + 6871040);              // 6 MB (NROWS*12B)
    unsigned short* tfeat = (unsigned short*)(ws + 13164544); // 8 MB

    prep_kernel<<<1188, 256, 0, stream>>>(xyz, newxyz, feat, tfeat,
                                          wf, w1, w2, wfb, w1b, w2b,
                                          stats, G1, G2);
    knn_kernel<<<NBATCH * NSAMP, 256, 0, stream>>>(xyz, newxyz, idxws, gxws);

    gxmoments_kernel<<<1024, 256, 0, stream>>>(gxws, stats);
    bn0_moments_finalize_kernel<<<1, 64, 0, stream>>>(stats, w0, b0, g0, be0, bnp);
    gram1_kernel<<<1024, 256, 0, stream>>>(gxws, w0, b0, bnp, G1, stats + 128);
    bn_gram_finalize_kernel<<<1, 256, 0, stream>>>(stats + 128, G1, w1, b1, g1, be1, bnp + 128);
    gram2_kernel<<<1024, 256, 0, stream>>>(gxws, w0, b0, b1, w1b, bnp, G2, stats + 192);
    bn_gram_finalize_kernel<<<1, 256, 0, stream>>>(stats + 192, G2, w2, b2, g2, be2, bnp + 256);

    final_conv_kernel<<<NBATCH * NSAMP / 8, 256, 0, stream>>>(
        gxws, idxws, tfeat, w0, b0, b1, b2, bnp, wfb, w1b, w2b, bf, ybuf, stats + 384);

    bn_finalize_kernel<<<1, 64, 0, stream>>>(stats + 384, gf, bef, bnp + 384, (float)(NBATCH * NSAMP));
    writeout_kernel<<<4096, 256, 0, stream>>>(ybuf, bnp + 384, outmain);
}